// Round 1
// baseline (141338.574 us; speedup 1.0000x reference)
//
#include <hip/hip_runtime.h>
#include <hip/hip_cooperative_groups.h>

namespace cg = cooperative_groups;

// Problem constants (fixed by setup_inputs)
#define BB 128
#define TT 512
#define FF 512
#define HH 512
#define G4 2048   // 4*H
#define KTOT 1024 // F + H
#define MT 64
#define NT 64
#define KC 32
#define KQ 4      // K split factor across blocks
#define NBLOCKS 256
#define NTHREADS 256

// Cooperative kernel: runs the full T-step recurrence for one layer.
// Grid: 256 blocks = (kq 0..3) x (mt 0..1) x (nt 0..31)
// Phase A: gates_partial[kq] = [x_t | h] tile @ [Wih | Whh]^T tile
// Phase B (blocks 0..127): per-batch-row L1 norms + gate nonlinearity + state update
__global__ __launch_bounds__(NTHREADS)
void lstm_layer(const float* __restrict__ Xin,   // [B, T, 512] input sequence
                const float* __restrict__ Wih,   // [2048, 512] this layer
                const float* __restrict__ Whh,   // [2048, 512] this layer
                const float* __restrict__ bih,   // [2048]
                const float* __restrict__ bhh,   // [2048]
                float* __restrict__ hst,         // [B, H] running h
                float* __restrict__ cst,         // [B, H] running c
                float* __restrict__ gpart,       // [KQ, B, 2048] partial gates
                float* __restrict__ Out)         // [B, T, 512] output sequence
{
    cg::grid_group grid = cg::this_grid();

    __shared__ float As[KC][MT + 4];   // stored transposed: As[k][m]
    __shared__ float Bs[KC][NT + 4];   // Bs[k][n]
    __shared__ float red[3][NTHREADS];

    const int tid = threadIdx.x;
    const int bid = blockIdx.x;
    const int kq = bid >> 6;           // 0..3
    const int mt = (bid >> 5) & 1;     // 0..1
    const int nt = bid & 31;           // 0..31
    const int m0 = mt * MT;
    const int n0 = nt * NT;
    const int kbase = kq * (KTOT / KQ); // 0,256,512,768

    const int tx = tid & 15;           // micro col group
    const int ty = tid >> 4;           // micro row group
    const int lr = tid >> 2;           // 0..63 staging row
    const int lc = (tid & 3) * 8;      // 0,8,16,24 staging col base

    for (int t = 0; t < TT; ++t) {
        // ---------------- Phase A: partial GEMM ----------------
        float acc[4][4];
        #pragma unroll
        for (int r = 0; r < 4; ++r)
            #pragma unroll
            for (int c = 0; c < 4; ++c) acc[r][c] = 0.f;

        for (int ks = 0; ks < (KTOT / KQ) / KC; ++ks) {  // 8 chunks of 32
            const int k0 = kbase + ks * KC;
            float4 a0, a1, b0, b1;
            if (k0 < FF) {
                // x part: A[m][k] = Xin[b=m][t][k], B[n][k] = Wih[n][k]
                const float* ap = Xin + ((size_t)(m0 + lr) * TT + t) * FF + k0 + lc;
                a0 = reinterpret_cast<const float4*>(ap)[0];
                a1 = reinterpret_cast<const float4*>(ap)[1];
                const float* bp = Wih + (size_t)(n0 + lr) * FF + k0 + lc;
                b0 = reinterpret_cast<const float4*>(bp)[0];
                b1 = reinterpret_cast<const float4*>(bp)[1];
            } else {
                // h part: A[m][k] = hst[b=m][k-F], B[n][k] = Whh[n][k-F]
                const int kh = k0 - FF;
                const float* ap = hst + (size_t)(m0 + lr) * HH + kh + lc;
                a0 = reinterpret_cast<const float4*>(ap)[0];
                a1 = reinterpret_cast<const float4*>(ap)[1];
                const float* bp = Whh + (size_t)(n0 + lr) * HH + kh + lc;
                b0 = reinterpret_cast<const float4*>(bp)[0];
                b1 = reinterpret_cast<const float4*>(bp)[1];
            }
            __syncthreads();  // previous chunk's reads done before overwrite
            As[lc + 0][lr] = a0.x; As[lc + 1][lr] = a0.y; As[lc + 2][lr] = a0.z; As[lc + 3][lr] = a0.w;
            As[lc + 4][lr] = a1.x; As[lc + 5][lr] = a1.y; As[lc + 6][lr] = a1.z; As[lc + 7][lr] = a1.w;
            Bs[lc + 0][lr] = b0.x; Bs[lc + 1][lr] = b0.y; Bs[lc + 2][lr] = b0.z; Bs[lc + 3][lr] = b0.w;
            Bs[lc + 4][lr] = b1.x; Bs[lc + 5][lr] = b1.y; Bs[lc + 6][lr] = b1.z; Bs[lc + 7][lr] = b1.w;
            __syncthreads();

            #pragma unroll
            for (int kk = 0; kk < KC; ++kk) {
                float4 a = *reinterpret_cast<const float4*>(&As[kk][4 * ty]);
                float4 b = *reinterpret_cast<const float4*>(&Bs[kk][4 * tx]);
                const float* aa = reinterpret_cast<const float*>(&a);
                const float* bb = reinterpret_cast<const float*>(&b);
                #pragma unroll
                for (int r = 0; r < 4; ++r)
                    #pragma unroll
                    for (int c = 0; c < 4; ++c)
                        acc[r][c] = fmaf(aa[r], bb[c], acc[r][c]);
            }
        }
        // write partial gates for this kq slice
        {
            float* gp = gpart + (size_t)kq * BB * G4;
            #pragma unroll
            for (int r = 0; r < 4; ++r) {
                const int m = m0 + 4 * ty + r;
                float4 v = make_float4(acc[r][0], acc[r][1], acc[r][2], acc[r][3]);
                *reinterpret_cast<float4*>(gp + (size_t)m * G4 + n0 + 4 * tx) = v;
            }
        }
        __threadfence();
        grid.sync();

        // ---------------- Phase B: nonlinearity + state update ----------------
        if (bid < BB) {
            const int b = bid;
            float gi[2], gf[2], gc[2], go[2];
            float si = 0.f, sf = 0.f, so = 0.f;
            #pragma unroll
            for (int u = 0; u < 2; ++u) {
                const int j = tid + u * NTHREADS;     // 0..511
                const size_t base = (size_t)b * G4 + j;
                float vi = 0.f, vf = 0.f, vc = 0.f, vo = 0.f;
                #pragma unroll
                for (int q = 0; q < KQ; ++q) {
                    const float* g = gpart + (size_t)q * BB * G4 + base;
                    vi += g[0];
                    vf += g[512];
                    vc += g[1024];
                    vo += g[1536];
                }
                vi += bih[j]        + bhh[j];
                vf += bih[512 + j]  + bhh[512 + j];
                vc += bih[1024 + j] + bhh[1024 + j];
                vo += bih[1536 + j] + bhh[1536 + j];
                gi[u] = vi; gf[u] = vf; gc[u] = vc; go[u] = vo;
                si += fabsf(vi); sf += fabsf(vf); so += fabsf(vo);
            }
            red[0][tid] = si; red[1][tid] = sf; red[2][tid] = so;
            __syncthreads();
            for (int s = NTHREADS / 2; s > 0; s >>= 1) {
                if (tid < s) {
                    red[0][tid] += red[0][tid + s];
                    red[1][tid] += red[1][tid + s];
                    red[2][tid] += red[2][tid + s];
                }
                __syncthreads();
            }
            const float Si = fmaxf(red[0][0], 1e-12f);
            const float Sf = fmaxf(red[1][0], 1e-12f);
            const float So = fmaxf(red[2][0], 1e-12f);
            #pragma unroll
            for (int u = 0; u < 2; ++u) {
                const int j = tid + u * NTHREADS;
                const float iv = 1.f / (1.f + expf(-gi[u] / Si));
                const float fv = 1.f / (1.f + expf(-gf[u] / Sf));
                const float ov = 1.f / (1.f + expf(-go[u] / So));
                const float cn = fv * cst[(size_t)b * HH + j] + iv * gc[u];
                const float hn = ov * fmaxf(cn, 0.f);
                cst[(size_t)b * HH + j] = cn;
                hst[(size_t)b * HH + j] = hn;
                Out[((size_t)b * TT + t) * HH + j] = hn;
            }
        }
        __threadfence();
        grid.sync();
    }
}

__global__ __launch_bounds__(256)
void init_state(const float* __restrict__ h0, const float* __restrict__ c0,
                float* __restrict__ hst, float* __restrict__ cst)
{
    const int idx = blockIdx.x * blockDim.x + threadIdx.x;
    if (idx >= 2 * BB * HH) return;
    const int l = idx / (BB * HH);
    const int r = idx % (BB * HH);   // b*H + j
    const int b = r / HH;
    const int j = r % HH;
    // h0/c0 layout: [B, L, H]
    hst[(size_t)l * BB * HH + r] = h0[((size_t)b * 2 + l) * HH + j];
    cst[(size_t)l * BB * HH + r] = c0[((size_t)b * 2 + l) * HH + j];
}

extern "C" void kernel_launch(void* const* d_in, const int* in_sizes, int n_in,
                              void* d_out, int out_size, void* d_ws, size_t ws_size,
                              hipStream_t stream)
{
    const float* x   = (const float*)d_in[0];
    const float* h0  = (const float*)d_in[1];
    const float* c0  = (const float*)d_in[2];
    const float* Wih = (const float*)d_in[3];
    const float* bih = (const float*)d_in[4];
    const float* Whh = (const float*)d_in[5];
    const float* bhh = (const float*)d_in[6];
    float* out = (float*)d_out;

    // ws layout (floats): hst[2][B*H], cst[2][B*H], gpart[KQ][B*G4]  (~5.25 MB)
    float* ws = (float*)d_ws;
    float* hst = ws;
    float* cst = ws + 2 * BB * HH;
    float* gpart = ws + 4 * BB * HH;

    hipLaunchKernelGGL(init_state, dim3((2 * BB * HH + 255) / 256), dim3(256), 0, stream,
                       h0, c0, hst, cst);

    for (int l = 0; l < 2; ++l) {
        const float* Xin   = (l == 0) ? x : (const float*)out;
        const float* wih_l = Wih + (size_t)l * G4 * FF;
        const float* whh_l = Whh + (size_t)l * G4 * HH;
        const float* bih_l = bih + (size_t)l * G4;
        const float* bhh_l = bhh + (size_t)l * G4;
        float* hst_l = hst + (size_t)l * BB * HH;
        float* cst_l = cst + (size_t)l * BB * HH;
        void* kargs[] = { (void*)&Xin, (void*)&wih_l, (void*)&whh_l,
                          (void*)&bih_l, (void*)&bhh_l,
                          (void*)&hst_l, (void*)&cst_l,
                          (void*)&gpart, (void*)&out };
        hipLaunchCooperativeKernel(reinterpret_cast<void*>(lstm_layer),
                                   dim3(NBLOCKS), dim3(NTHREADS),
                                   kargs, 0, stream);
    }
}

// Round 2
// 51899.298 us; speedup vs baseline: 2.7233x; 2.7233x over previous
//
#include <hip/hip_runtime.h>

#define T_SEQ 512
#define BB    128
#define HH    512
#define G4    2048
#define KH    512
#define NBLK  256
#define NTHR  256
#define KC    64
#define NCHUNK (KH / KC)   // 8

#define SCOPE __HIP_MEMORY_SCOPE_AGENT

typedef unsigned long long u64;

__device__ __forceinline__ float ldc(const float* p) {
    return __hip_atomic_load(p, __ATOMIC_RELAXED, SCOPE);
}
__device__ __forceinline__ void stc(float* p, float v) {
    __hip_atomic_store(p, v, __ATOMIC_RELAXED, SCOPE);
}
__device__ __forceinline__ u64 ldc64(const u64* p) {
    return __hip_atomic_load(p, __ATOMIC_RELAXED, SCOPE);
}
__device__ __forceinline__ void stc64(u64* p, u64 v) {
    __hip_atomic_store(p, v, __ATOMIC_RELAXED, SCOPE);
}
__device__ __forceinline__ u64 pack2(float a, float b) {
    union { float f[2]; u64 u; } x; x.f[0] = a; x.f[1] = b; return x.u;
}
__device__ __forceinline__ float2 unpack2(u64 v) {
    union { u64 u; float2 f; } x; x.u = v; return x.f;
}

// Lean grid barrier: monotonic counter, no cache maintenance.
// All cross-block data goes through sc1 (agent-scope) accesses, so no
// L2 writeback/invalidate is needed -- weights stay L2-resident.
__device__ __forceinline__ void gbar(unsigned* cnt, unsigned& epoch) {
    asm volatile("s_waitcnt vmcnt(0)" ::: "memory");  // drain this wave's stores
    __syncthreads();
    if (threadIdx.x == 0) {
        epoch += NBLK;
        __hip_atomic_fetch_add(cnt, 1u, __ATOMIC_RELAXED, SCOPE);
        while (__hip_atomic_load(cnt, __ATOMIC_RELAXED, SCOPE) < epoch) {
            __builtin_amdgcn_s_sleep(2);
        }
    }
    __syncthreads();
    asm volatile("" ::: "memory");
}

// Tiled GEMM for one 32x64 tile, K=512, acc 2 rows x 4 cols per thread.
// XPATH: A = Xin[b][tt][:] (plain cached loads).  !XPATH: A = hbuf (sc1 loads).
// B = packed weights [nt][512][64] (plain cached loads, L2-resident).
template<bool XPATH>
__device__ __forceinline__ void gemm_tile(
    const float* __restrict__ Asrc, int tt,
    const float* __restrict__ Wp,
    float acc[2][4],
    float (*As)[34], float* Bs,
    int b0, int tid)
{
    const int sr8 = tid >> 5;      // h staging: row 0..7
    const int sc2 = tid & 31;      // h staging: k-pair
    const int xr  = tid >> 4;      // x staging: row 0..15
    const int xc4 = tid & 15;      // x staging: k-quad
    const int ty  = tid >> 4;
    const int tx  = tid & 15;

    u64    vaH[2][4];
    float4 vaX[2][2];
    float4 vb[4];

    auto loadA = [&](int c, int s) {
        if (XPATH) {
            #pragma unroll
            for (int it = 0; it < 2; ++it) {
                const float* p = Asrc + ((size_t)(b0 + xr + 16*it) * T_SEQ + tt) * 512
                                 + c * KC + 4 * xc4;
                vaX[s][it] = *(const float4*)p;
            }
        } else {
            #pragma unroll
            for (int it = 0; it < 4; ++it) {
                const float* p = Asrc + (size_t)(b0 + sr8 + 8*it) * 512 + c * KC + 2 * sc2;
                vaH[s][it] = ldc64((const u64*)p);
            }
        }
    };
    auto loadB = [&](int c) {
        const float4* p = (const float4*)(Wp + (size_t)c * (KC * 64));
        #pragma unroll
        for (int it = 0; it < 4; ++it) vb[it] = p[tid + 256 * it];
    };
    auto writeLDS = [&](int s) {
        if (XPATH) {
            #pragma unroll
            for (int it = 0; it < 2; ++it) {
                As[4*xc4+0][xr+16*it] = vaX[s][it].x;
                As[4*xc4+1][xr+16*it] = vaX[s][it].y;
                As[4*xc4+2][xr+16*it] = vaX[s][it].z;
                As[4*xc4+3][xr+16*it] = vaX[s][it].w;
            }
        } else {
            #pragma unroll
            for (int it = 0; it < 4; ++it) {
                float2 f = unpack2(vaH[s][it]);
                As[2*sc2+0][sr8+8*it] = f.x;
                As[2*sc2+1][sr8+8*it] = f.y;
            }
        }
        #pragma unroll
        for (int it = 0; it < 4; ++it)
            ((float4*)Bs)[tid + 256 * it] = vb[it];
    };

    loadA(0, 0);
    loadB(0);
    loadA(1, 1);
    for (int c = 0; c < NCHUNK; ++c) {
        __syncthreads();
        writeLDS(c & 1);
        __syncthreads();
        if (c + 2 < NCHUNK) loadA(c + 2, c & 1);
        if (c + 1 < NCHUNK) loadB(c + 1);
        #pragma unroll
        for (int kk = 0; kk < KC; ++kk) {
            float2 a = *(const float2*)&As[kk][2 * ty];
            float4 b = *(const float4*)&Bs[kk * 64 + 4 * tx];
            acc[0][0] = fmaf(a.x, b.x, acc[0][0]);
            acc[0][1] = fmaf(a.x, b.y, acc[0][1]);
            acc[0][2] = fmaf(a.x, b.z, acc[0][2]);
            acc[0][3] = fmaf(a.x, b.w, acc[0][3]);
            acc[1][0] = fmaf(a.y, b.x, acc[1][0]);
            acc[1][1] = fmaf(a.y, b.y, acc[1][1]);
            acc[1][2] = fmaf(a.y, b.z, acc[1][2]);
            acc[1][3] = fmaf(a.y, b.w, acc[1][3]);
        }
    }
}

// One layer, persistent cooperative kernel.
// Blocks 0..127   : x-blocks, compute gx(t+1) = Wih @ x_{t+1} (one step ahead)
// Blocks 128..255 : h-blocks, compute gh(t) = Whh @ h_t, keep gates in regs,
//                   c-state in regs, L1-norms via shfl + atomicAdd.
__global__ __launch_bounds__(NTHR)
void lstm_layer(const float* __restrict__ Xin,
                const float* __restrict__ WpX,
                const float* __restrict__ WpH,
                const float* __restrict__ bsum,   // bih+bhh [2048]
                const float* __restrict__ c0l,    // c0 + l*512, idx b*1024+j
                float* __restrict__ hbuf,         // [128*512]  (sc1)
                float* __restrict__ gx,           // [2][128*2048] (sc1)
                float* __restrict__ norm,         // [2][128*4]    (sc1)
                unsigned* __restrict__ barcnt,
                float* __restrict__ Out)          // [B][T][512] plain
{
    __shared__ float As[KC][34];
    __shared__ float Bs[KC * 64];

    const int tid = threadIdx.x;
    const int bid = blockIdx.x;
    const bool isH = (bid >= 128);
    const int lb  = isH ? (bid - 128) : bid;
    const int mt  = lb >> 5;
    const int nt  = lb & 31;
    const int b0  = mt * 32;
    const int ty  = tid >> 4;
    const int tx  = tid & 15;
    const int r0  = b0 + 2 * ty;
    const int jj  = nt * 16 + tx;

    const float* Wp = (isH ? WpH : WpX) + (size_t)nt * (KH * 64);

    unsigned epoch = 0;
    float creg[2] = {0.f, 0.f};
    if (isH) {
        creg[0] = c0l[(size_t)(r0 + 0) * 1024 + jj];
        creg[1] = c0l[(size_t)(r0 + 1) * 1024 + jj];
    }

    // pre-loop: x-blocks produce gx(0)
    if (!isH) {
        float acc[2][4] = {};
        gemm_tile<true>(Xin, 0, Wp, acc, As, Bs, b0, tid);
        #pragma unroll
        for (int r = 0; r < 2; ++r) {
            float* q = gx + (size_t)(r0 + r) * G4 + nt * 64 + 4 * tx;
            stc64((u64*)q,       pack2(acc[r][0], acc[r][1]));
            stc64((u64*)(q + 2), pack2(acc[r][2], acc[r][3]));
        }
    }
    gbar(barcnt, epoch);

    for (int t = 0; t < T_SEQ; ++t) {
        const int p = t & 1;
        float gv[2][4];

        if (isH) {
            float acc[2][4] = {};
            gemm_tile<false>(hbuf, 0, Wp, acc, As, Bs, b0, tid);
            const float* gp = gx + (size_t)p * (BB * G4);
            float sa[2][3];
            #pragma unroll
            for (int r = 0; r < 2; ++r) {
                const int b = r0 + r;
                #pragma unroll
                for (int g = 0; g < 4; ++g) {
                    const int col = g * 512 + jj;
                    gv[r][g] = acc[r][g] + ldc(gp + (size_t)b * G4 + col) + bsum[col];
                }
                sa[r][0] = fabsf(gv[r][0]);
                sa[r][1] = fabsf(gv[r][1]);
                sa[r][2] = fabsf(gv[r][3]);
            }
            #pragma unroll
            for (int d = 1; d < 16; d <<= 1) {
                #pragma unroll
                for (int r = 0; r < 2; ++r) {
                    sa[r][0] += __shfl_xor(sa[r][0], d, 16);
                    sa[r][1] += __shfl_xor(sa[r][1], d, 16);
                    sa[r][2] += __shfl_xor(sa[r][2], d, 16);
                }
            }
            if (tx == 0) {
                float* np = norm + (size_t)p * 512;
                #pragma unroll
                for (int r = 0; r < 2; ++r) {
                    __hip_atomic_fetch_add(np + (r0+r)*4 + 0, sa[r][0], __ATOMIC_RELAXED, SCOPE);
                    __hip_atomic_fetch_add(np + (r0+r)*4 + 1, sa[r][1], __ATOMIC_RELAXED, SCOPE);
                    __hip_atomic_fetch_add(np + (r0+r)*4 + 2, sa[r][2], __ATOMIC_RELAXED, SCOPE);
                }
            }
        } else if (t + 1 < T_SEQ) {
            float acc[2][4] = {};
            gemm_tile<true>(Xin, t + 1, Wp, acc, As, Bs, b0, tid);
            float* gp = gx + (size_t)((t + 1) & 1) * (BB * G4);
            #pragma unroll
            for (int r = 0; r < 2; ++r) {
                float* q = gp + (size_t)(r0 + r) * G4 + nt * 64 + 4 * tx;
                stc64((u64*)q,       pack2(acc[r][0], acc[r][1]));
                stc64((u64*)(q + 2), pack2(acc[r][2], acc[r][3]));
            }
        }
        gbar(barcnt, epoch);

        if (isH) {
            const float* np = norm + (size_t)p * 512;
            #pragma unroll
            for (int r = 0; r < 2; ++r) {
                const int b = r0 + r;
                const float Si = fmaxf(ldc(np + b*4 + 0), 1e-12f);
                const float Sf = fmaxf(ldc(np + b*4 + 1), 1e-12f);
                const float So = fmaxf(ldc(np + b*4 + 2), 1e-12f);
                const float iv = 1.f / (1.f + expf(-gv[r][0] / Si));
                const float fv = 1.f / (1.f + expf(-gv[r][1] / Sf));
                const float ov = 1.f / (1.f + expf(-gv[r][3] / So));
                const float cn = fv * creg[r] + iv * gv[r][2];
                creg[r] = cn;
                const float hn = ov * fmaxf(cn, 0.f);
                stc(hbuf + (size_t)b * 512 + jj, hn);
                Out[((size_t)b * T_SEQ + t) * 512 + jj] = hn;
            }
        } else if (bid == 0) {
            float* nz = norm + (size_t)((t + 1) & 1) * 512;
            stc(nz + tid, 0.f);
            stc(nz + tid + 256, 0.f);
        }
        gbar(barcnt, epoch);
    }
}

// Pack weights: WpX[l][nt][k][c] = Wih[l][nt*64+c][k]
//               WpH[l][nt][k][tx*4+g] = Whh[l][g*512+nt*16+tx][k]
// Also bsum = bih + bhh.
__global__ __launch_bounds__(256)
void pack_w(const float* __restrict__ Wih, const float* __restrict__ Whh,
            const float* __restrict__ bih, const float* __restrict__ bhh,
            float* __restrict__ WpX, float* __restrict__ WpH, float* __restrict__ bsum)
{
    __shared__ float tile[64][65];
    const int tid = threadIdx.x;
    const int blk = blockIdx.x;
    if (blk < 16) bsum[blk * 256 + tid] = bih[blk * 256 + tid] + bhh[blk * 256 + tid];

    const int mat = blk & 1;
    const int kc  = (blk >> 1) & 7;
    const int nt  = (blk >> 4) & 31;
    const int l   = blk >> 9;
    const float* W = mat ? Whh : Wih;
    float* Wp = mat ? WpH : WpX;

    const int c  = tid >> 2;
    const int ko = (tid & 3) * 16;
    const int grow = mat ? ((c & 3) * 512 + nt * 16 + (c >> 2))
                         : (nt * 64 + c);
    const float* src = W + ((size_t)(l * G4 + grow)) * 512 + kc * 64 + ko;
    #pragma unroll
    for (int it = 0; it < 4; ++it) {
        float4 v = ((const float4*)src)[it];
        tile[c][ko + 4*it + 0] = v.x;
        tile[c][ko + 4*it + 1] = v.y;
        tile[c][ko + 4*it + 2] = v.z;
        tile[c][ko + 4*it + 3] = v.w;
    }
    __syncthreads();
    const int k  = tid >> 2;
    const int co = (tid & 3) * 16;
    float* dst = Wp + ((size_t)((l * 32 + nt) * 512) + kc * 64 + k) * 64 + co;
    #pragma unroll
    for (int it = 0; it < 4; ++it) {
        float4 v;
        v.x = tile[co + 4*it + 0][k];
        v.y = tile[co + 4*it + 1][k];
        v.z = tile[co + 4*it + 2][k];
        v.w = tile[co + 4*it + 3][k];
        ((float4*)dst)[it] = v;
    }
}

__global__ __launch_bounds__(256)
void init_layer(const float* __restrict__ h0l, float* __restrict__ hbuf,
                float* __restrict__ norm, unsigned* __restrict__ barcnt)
{
    const int idx = blockIdx.x * blockDim.x + threadIdx.x;
    if (idx == 0) *barcnt = 0u;
    if (idx < 1024) norm[idx] = 0.f;
    if (idx < BB * HH) {
        const int b = idx >> 9, j = idx & 511;
        hbuf[idx] = h0l[(size_t)b * 1024 + j];
    }
}

extern "C" void kernel_launch(void* const* d_in, const int* in_sizes, int n_in,
                              void* d_out, int out_size, void* d_ws, size_t ws_size,
                              hipStream_t stream)
{
    const float* x   = (const float*)d_in[0];
    const float* h0  = (const float*)d_in[1];
    const float* c0  = (const float*)d_in[2];
    const float* Wih = (const float*)d_in[3];
    const float* bih = (const float*)d_in[4];
    const float* Whh = (const float*)d_in[5];
    const float* bhh = (const float*)d_in[6];
    float* out = (float*)d_out;
    float* ws  = (float*)d_ws;

    // ws layout (floats)
    unsigned* barcnt = (unsigned*)ws;                 // 32 floats reserved
    float* norm = ws + 32;                            // 1024
    float* hbuf = norm + 1024;                        // 65536
    float* gx   = hbuf + BB * HH;                     // 2*128*2048 = 524288
    float* WpX  = gx + 2 * BB * G4;                   // 2*32*512*64 = 2097152
    float* WpH  = WpX + 2 * 32 * 512 * 64;            // 2097152
    float* bsum = WpH + 2 * 32 * 512 * 64;            // 4096
    // total ~19.2 MB

    hipLaunchKernelGGL(pack_w, dim3(1024), dim3(256), 0, stream,
                       Wih, Whh, bih, bhh, WpX, WpH, bsum);

    for (int l = 0; l < 2; ++l) {
        hipLaunchKernelGGL(init_layer, dim3(256), dim3(256), 0, stream,
                           h0 + l * 512, hbuf, norm, barcnt);
        const float* Xin  = (l == 0) ? x : (const float*)out;
        const float* WpXl = WpX + (size_t)l * 32 * 512 * 64;
        const float* WpHl = WpH + (size_t)l * 32 * 512 * 64;
        const float* bsl  = bsum + l * 2048;
        const float* c0l  = c0 + l * 512;
        void* args[] = {(void*)&Xin, (void*)&WpXl, (void*)&WpHl, (void*)&bsl, (void*)&c0l,
                        (void*)&hbuf, (void*)&gx, (void*)&norm, (void*)&barcnt, (void*)&out};
        hipLaunchCooperativeKernel(reinterpret_cast<void*>(lstm_layer),
                                   dim3(NBLK), dim3(NTHR), args, 0, stream);
    }
}

// Round 4
// 45930.499 us; speedup vs baseline: 3.0772x; 1.1300x over previous
//
#include <hip/hip_runtime.h>

#define T_SEQ 512
#define BB    128
#define HH    512
#define G4    2048
#define KH    512
#define NBLK  256
#define NTHR  256
#define KC    64
#define NCHUNK (KH / KC)   // 8
#define GARRIVE 64         // blocks per mt-group barrier (32 x + 32 h)

#define SCOPE __HIP_MEMORY_SCOPE_AGENT

typedef unsigned long long u64;
typedef unsigned u32;

__device__ __forceinline__ float ldc(const float* p) {
    return __hip_atomic_load(p, __ATOMIC_RELAXED, SCOPE);
}
__device__ __forceinline__ void stc(float* p, float v) {
    __hip_atomic_store(p, v, __ATOMIC_RELAXED, SCOPE);
}
__device__ __forceinline__ u64 ldc64(const u64* p) {
    return __hip_atomic_load(p, __ATOMIC_RELAXED, SCOPE);
}
__device__ __forceinline__ void stc64(u64* p, u64 v) {
    __hip_atomic_store(p, v, __ATOMIC_RELAXED, SCOPE);
}
__device__ __forceinline__ u64 pack2(float a, float b) {
    union { float f[2]; u64 u; } x; x.f[0] = a; x.f[1] = b; return x.u;
}
__device__ __forceinline__ float2 unpack2(u64 v) {
    union { u64 u; float2 f; } x; x.u = v; return x.f;
}

// Per-mt-group barrier: 64 arrivals on a group-private counter (monotonic).
// All cross-block data moves via sc1 (agent-scope) accesses, so no L2
// writeback/invalidate is needed -- weights stay L2-resident.
__device__ __forceinline__ void gbar(u32* cnt, u32& epoch) {
    asm volatile("s_waitcnt vmcnt(0)" ::: "memory");  // drain this wave's stores
    __syncthreads();
    if (threadIdx.x == 0) {
        epoch += GARRIVE;
        __hip_atomic_fetch_add(cnt, 1u, __ATOMIC_RELAXED, SCOPE);
        while ((int)(__hip_atomic_load(cnt, __ATOMIC_RELAXED, SCOPE) - epoch) < 0)
            __builtin_amdgcn_s_sleep(2);
    }
    __syncthreads();
    asm volatile("" ::: "memory");
}

// Tiled GEMM for one 32x64 tile, K=512, acc 2 rows x 4 cols per thread.
// XPATH: A = Xin[b][tt][:] (plain cached loads).  !XPATH: A = hbuf (sc1 loads).
// B = packed weights (plain cached loads, L2-resident).
template<bool XPATH>
__device__ __forceinline__ void gemm_tile(
    const float* __restrict__ Asrc, int tt,
    const float* __restrict__ Wp,
    float acc[2][4],
    float (*As)[34], float* Bs,
    int b0, int tid)
{
    const int sr8 = tid >> 5;      // h staging: row 0..7
    const int sc2 = tid & 31;      // h staging: k-pair
    const int xr  = tid >> 4;      // x staging: row 0..15
    const int xc4 = tid & 15;      // x staging: k-quad
    const int ty  = tid >> 4;
    const int tx  = tid & 15;

    u64    vaH[2][4];
    float4 vaX[2][2];
    float4 vb[4];

    auto loadA = [&](int c, int s) {
        if (XPATH) {
            #pragma unroll
            for (int it = 0; it < 2; ++it) {
                const float* p = Asrc + ((size_t)(b0 + xr + 16*it) * T_SEQ + tt) * 512
                                 + c * KC + 4 * xc4;
                vaX[s][it] = *(const float4*)p;
            }
        } else {
            #pragma unroll
            for (int it = 0; it < 4; ++it) {
                const float* p = Asrc + (size_t)(b0 + sr8 + 8*it) * 512 + c * KC + 2 * sc2;
                vaH[s][it] = ldc64((const u64*)p);
            }
        }
    };
    auto loadB = [&](int c) {
        const float4* p = (const float4*)(Wp + (size_t)c * (KC * 64));
        #pragma unroll
        for (int it = 0; it < 4; ++it) vb[it] = p[tid + 256 * it];
    };
    auto writeLDS = [&](int s) {
        if (XPATH) {
            #pragma unroll
            for (int it = 0; it < 2; ++it) {
                As[4*xc4+0][xr+16*it] = vaX[s][it].x;
                As[4*xc4+1][xr+16*it] = vaX[s][it].y;
                As[4*xc4+2][xr+16*it] = vaX[s][it].z;
                As[4*xc4+3][xr+16*it] = vaX[s][it].w;
            }
        } else {
            #pragma unroll
            for (int it = 0; it < 4; ++it) {
                float2 f = unpack2(vaH[s][it]);
                As[2*sc2+0][sr8+8*it] = f.x;
                As[2*sc2+1][sr8+8*it] = f.y;
            }
        }
        #pragma unroll
        for (int it = 0; it < 4; ++it)
            ((float4*)Bs)[tid + 256 * it] = vb[it];
    };

    loadA(0, 0);
    loadB(0);
    loadA(1, 1);
    for (int c = 0; c < NCHUNK; ++c) {
        __syncthreads();
        writeLDS(c & 1);
        __syncthreads();
        if (c + 2 < NCHUNK) loadA(c + 2, c & 1);
        if (c + 1 < NCHUNK) loadB(c + 1);
        #pragma unroll
        for (int kk = 0; kk < KC; ++kk) {
            float2 a = *(const float2*)&As[kk][2 * ty];
            float4 b = *(const float4*)&Bs[kk * 64 + 4 * tx];
            acc[0][0] = fmaf(a.x, b.x, acc[0][0]);
            acc[0][1] = fmaf(a.x, b.y, acc[0][1]);
            acc[0][2] = fmaf(a.x, b.z, acc[0][2]);
            acc[0][3] = fmaf(a.x, b.w, acc[0][3]);
            acc[1][0] = fmaf(a.y, b.x, acc[1][0]);
            acc[1][1] = fmaf(a.y, b.y, acc[1][1]);
            acc[1][2] = fmaf(a.y, b.z, acc[1][2]);
            acc[1][3] = fmaf(a.y, b.w, acc[1][3]);
        }
    }
}

// One layer, persistent cooperative kernel, per-mt-group barriers.
// Blocks 0..127   : x-blocks (mt,nt), compute gx(t+1) = Wih @ x_{t+1} (one step ahead)
// Blocks 128..255 : h-blocks (mt,nt), compute gh(t) = Whh @ h_t, gates in regs,
//                   c-state in regs, L1-norms via shfl + atomicAdd.
// All dataflow is mt-group-local, so a 64-block group barrier suffices.
__global__ __launch_bounds__(NTHR)
void lstm_layer(const float* __restrict__ Xin,
                const float* __restrict__ WpX,
                const float* __restrict__ WpH,
                const float* __restrict__ bsum,   // bih+bhh [2048]
                const float* __restrict__ c0l,    // c0 + l*512, idx b*1024+j
                float* __restrict__ hbuf,         // [128*512]     (sc1)
                float* __restrict__ gx,           // [2][128*2048] (sc1)
                float* __restrict__ norm,         // [2][128*4]    (sc1)
                u32*   __restrict__ cnts,         // group barrier counters
                float* __restrict__ Out)          // [B][T][512] plain
{
    __shared__ float As[KC][34];
    __shared__ float Bs[KC * 64];

    const int tid = threadIdx.x;
    const int bid = blockIdx.x;
    const bool isH = (bid >= 128);
    const int lb  = isH ? (bid - 128) : bid;
    const int mt  = lb >> 5;
    const int nt  = lb & 31;
    const int b0  = mt * 32;
    const int ty  = tid >> 4;
    const int tx  = tid & 15;
    const int r0  = b0 + 2 * ty;
    const int jj  = nt * 16 + tx;

    u32* gcnt = cnts + mt * 64;     // 256B spacing between group counters
    u32 epoch = 0;

    const float* Wp = (isH ? WpH : WpX) + (size_t)nt * (KH * 64);

    float creg[2] = {0.f, 0.f};
    if (isH) {
        creg[0] = c0l[(size_t)(r0 + 0) * 1024 + jj];
        creg[1] = c0l[(size_t)(r0 + 1) * 1024 + jj];
    }

    // pre-loop: x-blocks produce gx(0) into slot 0
    if (!isH) {
        float acc[2][4] = {};
        gemm_tile<true>(Xin, 0, Wp, acc, As, Bs, b0, tid);
        #pragma unroll
        for (int r = 0; r < 2; ++r) {
            float* q = gx + (size_t)(r0 + r) * G4 + nt * 64 + 4 * tx;
            stc64((u64*)q,       pack2(acc[r][0], acc[r][1]));
            stc64((u64*)(q + 2), pack2(acc[r][2], acc[r][3]));
        }
    }
    gbar(gcnt, epoch);

    for (int t = 0; t < T_SEQ; ++t) {
        const int p = t & 1;
        float gv[2][4];

        // ---------------- Phase A ----------------
        if (isH) {
            float acc[2][4] = {};
            gemm_tile<false>(hbuf, 0, Wp, acc, As, Bs, b0, tid);
            const float* gp = gx + (size_t)p * (BB * G4);
            float sa[2][3];
            #pragma unroll
            for (int r = 0; r < 2; ++r) {
                const int b = r0 + r;
                #pragma unroll
                for (int g = 0; g < 4; ++g) {
                    const int col = g * 512 + jj;
                    gv[r][g] = acc[r][g] + ldc(gp + (size_t)b * G4 + col) + bsum[col];
                }
                sa[r][0] = fabsf(gv[r][0]);
                sa[r][1] = fabsf(gv[r][1]);
                sa[r][2] = fabsf(gv[r][3]);
            }
            #pragma unroll
            for (int d = 1; d < 16; d <<= 1) {
                #pragma unroll
                for (int r = 0; r < 2; ++r) {
                    sa[r][0] += __shfl_xor(sa[r][0], d, 16);
                    sa[r][1] += __shfl_xor(sa[r][1], d, 16);
                    sa[r][2] += __shfl_xor(sa[r][2], d, 16);
                }
            }
            if (tx == 0) {
                float* np = norm + (size_t)p * 512;
                #pragma unroll
                for (int r = 0; r < 2; ++r) {
                    __hip_atomic_fetch_add(np + (r0+r)*4 + 0, sa[r][0], __ATOMIC_RELAXED, SCOPE);
                    __hip_atomic_fetch_add(np + (r0+r)*4 + 1, sa[r][1], __ATOMIC_RELAXED, SCOPE);
                    __hip_atomic_fetch_add(np + (r0+r)*4 + 2, sa[r][2], __ATOMIC_RELAXED, SCOPE);
                }
            }
        } else if (t + 1 < T_SEQ) {
            float acc[2][4] = {};
            gemm_tile<true>(Xin, t + 1, Wp, acc, As, Bs, b0, tid);
            float* gp = gx + (size_t)((t + 1) & 1) * (BB * G4);
            #pragma unroll
            for (int r = 0; r < 2; ++r) {
                float* q = gp + (size_t)(r0 + r) * G4 + nt * 64 + 4 * tx;
                stc64((u64*)q,       pack2(acc[r][0], acc[r][1]));
                stc64((u64*)(q + 2), pack2(acc[r][2], acc[r][3]));
            }
        }
        gbar(gcnt, epoch);

        // ---------------- Phase B ----------------
        if (isH) {
            const float* np = norm + (size_t)p * 512;
            #pragma unroll
            for (int r = 0; r < 2; ++r) {
                const int b = r0 + r;
                const float Si = fmaxf(ldc(np + b*4 + 0), 1e-12f);
                const float Sf = fmaxf(ldc(np + b*4 + 1), 1e-12f);
                const float So = fmaxf(ldc(np + b*4 + 2), 1e-12f);
                const float iv = 1.f / (1.f + expf(-gv[r][0] / Si));
                const float fv = 1.f / (1.f + expf(-gv[r][1] / Sf));
                const float ov = 1.f / (1.f + expf(-gv[r][3] / So));
                const float cn = fv * creg[r] + iv * gv[r][2];
                creg[r] = cn;
                const float hn = ov * fmaxf(cn, 0.f);
                stc(hbuf + (size_t)b * 512 + jj, hn);
                Out[((size_t)b * T_SEQ + t) * 512 + jj] = hn;
            }
        } else if (nt == 0) {
            // zero this group's norm slot for step t+1 (rows b0..b0+31)
            if (tid < 128) {
                float* nz = norm + (size_t)((t + 1) & 1) * 512;
                stc(nz + b0 * 4 + tid, 0.f);
            }
        }
        gbar(gcnt, epoch);
    }
}

// Pack weights: WpX[l][nt][k][c] = Wih[l][nt*64+c][k]
//               WpH[l][nt][k][tx*4+g] = Whh[l][g*512+nt*16+tx][k]
// Also bsum = bih + bhh.
__global__ __launch_bounds__(256)
void pack_w(const float* __restrict__ Wih, const float* __restrict__ Whh,
            const float* __restrict__ bih, const float* __restrict__ bhh,
            float* __restrict__ WpX, float* __restrict__ WpH, float* __restrict__ bsum)
{
    __shared__ float tile[64][65];
    const int tid = threadIdx.x;
    const int blk = blockIdx.x;
    if (blk < 16) bsum[blk * 256 + tid] = bih[blk * 256 + tid] + bhh[blk * 256 + tid];

    const int mat = blk & 1;
    const int kc  = (blk >> 1) & 7;
    const int nt  = (blk >> 4) & 31;
    const int l   = blk >> 9;
    const float* W = mat ? Whh : Wih;
    float* Wp = mat ? WpH : WpX;

    const int c  = tid >> 2;
    const int ko = (tid & 3) * 16;
    const int grow = mat ? ((c & 3) * 512 + nt * 16 + (c >> 2))
                         : (nt * 64 + c);
    const float* src = W + ((size_t)(l * G4 + grow)) * 512 + kc * 64 + ko;
    #pragma unroll
    for (int it = 0; it < 4; ++it) {
        float4 v = ((const float4*)src)[it];
        tile[c][ko + 4*it + 0] = v.x;
        tile[c][ko + 4*it + 1] = v.y;
        tile[c][ko + 4*it + 2] = v.z;
        tile[c][ko + 4*it + 3] = v.w;
    }
    __syncthreads();
    const int k  = tid >> 2;
    const int co = (tid & 3) * 16;
    float* dst = Wp + ((size_t)((l * 32 + nt) * 512) + kc * 64 + k) * 64 + co;
    #pragma unroll
    for (int it = 0; it < 4; ++it) {
        float4 v;
        v.x = tile[co + 4*it + 0][k];
        v.y = tile[co + 4*it + 1][k];
        v.z = tile[co + 4*it + 2][k];
        v.w = tile[co + 4*it + 3][k];
        ((float4*)dst)[it] = v;
    }
}

__global__ __launch_bounds__(256)
void init_layer(const float* __restrict__ h0l, float* __restrict__ hbuf,
                float* __restrict__ norm, u32* __restrict__ cnts)
{
    const int idx = blockIdx.x * blockDim.x + threadIdx.x;
    if (idx < 256) cnts[idx] = 0u;
    if (idx < 1024) norm[idx] = 0.f;
    if (idx < BB * HH) {
        const int b = idx >> 9, j = idx & 511;
        hbuf[idx] = h0l[(size_t)b * 1024 + j];
    }
}

extern "C" void kernel_launch(void* const* d_in, const int* in_sizes, int n_in,
                              void* d_out, int out_size, void* d_ws, size_t ws_size,
                              hipStream_t stream)
{
    const float* x   = (const float*)d_in[0];
    const float* h0  = (const float*)d_in[1];
    const float* c0  = (const float*)d_in[2];
    const float* Wih = (const float*)d_in[3];
    const float* bih = (const float*)d_in[4];
    const float* Whh = (const float*)d_in[5];
    const float* bhh = (const float*)d_in[6];
    float* out = (float*)d_out;
    float* ws  = (float*)d_ws;

    // ws layout (floats), total ~18.3 MB
    u32*   cnts = (u32*)ws;                    // 256 u32
    float* norm = ws + 256;                    // 1024
    float* hbuf = norm + 1024;                 // 65536
    float* gx   = hbuf + BB * HH;              // 2*128*2048 = 524288
    float* WpX  = gx + 2 * BB * G4;            // 2097152
    float* WpH  = WpX + 2 * 32 * 512 * 64;     // 2097152
    float* bsum = WpH + 2 * 32 * 512 * 64;     // 4096

    hipLaunchKernelGGL(pack_w, dim3(1024), dim3(256), 0, stream,
                       Wih, Whh, bih, bhh, WpX, WpH, bsum);

    for (int l = 0; l < 2; ++l) {
        hipLaunchKernelGGL(init_layer, dim3(256), dim3(256), 0, stream,
                           h0 + l * 512, hbuf, norm, cnts);
        const float* Xin  = (l == 0) ? x : (const float*)out;
        const float* WpXl = WpX + (size_t)l * 32 * 512 * 64;
        const float* WpHl = WpH + (size_t)l * 32 * 512 * 64;
        const float* bsl  = bsum + l * 2048;
        const float* c0l  = c0 + l * 512;
        void* args[] = {(void*)&Xin, (void*)&WpXl, (void*)&WpHl, (void*)&bsl, (void*)&c0l,
                        (void*)&hbuf, (void*)&gx, (void*)&norm, (void*)&cnts, (void*)&out};
        hipLaunchCooperativeKernel(reinterpret_cast<void*>(lstm_layer),
                                   dim3(NBLK), dim3(NTHR), args, 0, stream);
    }
}

// Round 6
// 45736.429 us; speedup vs baseline: 3.0903x; 1.0042x over previous
//
#include <hip/hip_runtime.h>

#define T_SEQ 512
#define BB    128
#define HH    512
#define G4    2048
#define KH    512
#define NBLK  256
#define NTHR  256
#define KC    64
#define NCHUNK (KH / KC)   // 8

#define SCOPE __HIP_MEMORY_SCOPE_AGENT

typedef unsigned long long u64;
typedef unsigned u32;

__device__ __forceinline__ float ldc(const float* p) {
    return __hip_atomic_load(p, __ATOMIC_RELAXED, SCOPE);
}
__device__ __forceinline__ void stc(float* p, float v) {
    __hip_atomic_store(p, v, __ATOMIC_RELAXED, SCOPE);
}
__device__ __forceinline__ u64 ldc64(const u64* p) {
    return __hip_atomic_load(p, __ATOMIC_RELAXED, SCOPE);
}
__device__ __forceinline__ void stc64(u64* p, u64 v) {
    __hip_atomic_store(p, v, __ATOMIC_RELAXED, SCOPE);
}
__device__ __forceinline__ u32 ldcu(const u32* p) {
    return __hip_atomic_load(p, __ATOMIC_RELAXED, SCOPE);
}
__device__ __forceinline__ void stcu(u32* p, u32 v) {
    __hip_atomic_store(p, v, __ATOMIC_RELAXED, SCOPE);
}
__device__ __forceinline__ u64 pack2(float a, float b) {
    union { float f[2]; u64 u; } x; x.f[0] = a; x.f[1] = b; return x.u;
}
__device__ __forceinline__ float2 unpack2(u64 v) {
    union { u64 u; float2 f; } x; x.u = v; return x.f;
}

// Per-mt-group joint barrier, NO RMW: arrival = one flag store (own slot),
// detection = wave 0 loads all 64 flags in parallel + __all ballot.
// Flags are monotonic epochs (1..1025), zeroed per launch by init_layer.
// All cross-block data moves via sc1 (agent-scope) accesses, so no L2
// writeback/invalidate is needed -- weights stay L2-resident.
__device__ __forceinline__ void gbar(u32* gf, u32 e, int wg, int tid) {
    asm volatile("s_waitcnt vmcnt(0)" ::: "memory");  // drain this wave's stores
    __syncthreads();
    if (tid == 0) stcu(gf + wg, e);
    if (tid < 64) {
        const u32* p = gf + tid;
        for (;;) {
            u32 v = ldcu(p);
            if (__all((int)(v - e) >= 0)) break;
            __builtin_amdgcn_s_sleep(1);
        }
    }
    __syncthreads();
    asm volatile("" ::: "memory");
}

// Tiled GEMM for one 32x64 tile, K=512, acc 2 rows x 4 cols per thread.
// XPATH: A = Xin[b][tt][:] (plain cached loads).  !XPATH: A = hbuf (sc1 loads).
// B = packed weights (plain cached loads, L2-resident).
template<bool XPATH>
__device__ __forceinline__ void gemm_tile(
    const float* __restrict__ Asrc, int tt,
    const float* __restrict__ Wp,
    float acc[2][4],
    float (*As)[34], float* Bs,
    int b0, int tid)
{
    const int sr8 = tid >> 5;      // h staging: row 0..7
    const int sc2 = tid & 31;      // h staging: k-pair
    const int xr  = tid >> 4;      // x staging: row 0..15
    const int xc4 = tid & 15;      // x staging: k-quad
    const int ty  = tid >> 4;
    const int tx  = tid & 15;

    u64    vaH[2][4];
    float4 vaX[2][2];
    float4 vb[4];

    auto loadA = [&](int c, int s) {
        if (XPATH) {
            #pragma unroll
            for (int it = 0; it < 2; ++it) {
                const float* p = Asrc + ((size_t)(b0 + xr + 16*it) * T_SEQ + tt) * 512
                                 + c * KC + 4 * xc4;
                vaX[s][it] = *(const float4*)p;
            }
        } else {
            #pragma unroll
            for (int it = 0; it < 4; ++it) {
                const float* p = Asrc + (size_t)(b0 + sr8 + 8*it) * 512 + c * KC + 2 * sc2;
                vaH[s][it] = ldc64((const u64*)p);
            }
        }
    };
    auto loadB = [&](int c) {
        const float4* p = (const float4*)(Wp + (size_t)c * (KC * 64));
        #pragma unroll
        for (int it = 0; it < 4; ++it) vb[it] = p[tid + 256 * it];
    };
    auto writeLDS = [&](int s) {
        if (XPATH) {
            #pragma unroll
            for (int it = 0; it < 2; ++it) {
                As[4*xc4+0][xr+16*it] = vaX[s][it].x;
                As[4*xc4+1][xr+16*it] = vaX[s][it].y;
                As[4*xc4+2][xr+16*it] = vaX[s][it].z;
                As[4*xc4+3][xr+16*it] = vaX[s][it].w;
            }
        } else {
            #pragma unroll
            for (int it = 0; it < 4; ++it) {
                float2 f = unpack2(vaH[s][it]);
                As[2*sc2+0][sr8+8*it] = f.x;
                As[2*sc2+1][sr8+8*it] = f.y;
            }
        }
        #pragma unroll
        for (int it = 0; it < 4; ++it)
            ((float4*)Bs)[tid + 256 * it] = vb[it];
    };

    loadA(0, 0);
    loadB(0);
    loadA(1, 1);
    for (int c = 0; c < NCHUNK; ++c) {
        __syncthreads();
        writeLDS(c & 1);
        __syncthreads();
        if (c + 2 < NCHUNK) loadA(c + 2, c & 1);
        if (c + 1 < NCHUNK) loadB(c + 1);
        #pragma unroll
        for (int kk = 0; kk < KC; ++kk) {
            float2 a = *(const float2*)&As[kk][2 * ty];
            float4 b = *(const float4*)&Bs[kk * 64 + 4 * tx];
            acc[0][0] = fmaf(a.x, b.x, acc[0][0]);
            acc[0][1] = fmaf(a.x, b.y, acc[0][1]);
            acc[0][2] = fmaf(a.x, b.z, acc[0][2]);
            acc[0][3] = fmaf(a.x, b.w, acc[0][3]);
            acc[1][0] = fmaf(a.y, b.x, acc[1][0]);
            acc[1][1] = fmaf(a.y, b.y, acc[1][1]);
            acc[1][2] = fmaf(a.y, b.z, acc[1][2]);
            acc[1][3] = fmaf(a.y, b.w, acc[1][3]);
        }
    }
}

// One layer, persistent cooperative kernel, per-mt-group joint barriers (flag-based).
// Blocks 0..127   : x-blocks (mt,nt), compute gx(t+1) = Wih @ x_{t+1} (one step ahead)
// Blocks 128..255 : h-blocks (mt,nt), compute gh(t) = Whh @ h_t, gates in regs,
//                   c-state in regs, L1-norms via shfl + partial stores (no atomics).
// All dataflow is mt-group-local, so a 64-block group barrier suffices.
__global__ __launch_bounds__(NTHR)
void lstm_layer(const float* __restrict__ Xin,
                const float* __restrict__ WpX,
                const float* __restrict__ WpH,
                const float* __restrict__ bsum,   // bih+bhh [2048]
                const float* __restrict__ c0l,    // c0 + l*512, idx b*1024+j
                float* __restrict__ hbuf,         // [128*512]        (sc1)
                float* __restrict__ gx,           // [2][128*2048]    (sc1)
                float* __restrict__ part,         // [4][32][32][4]   (sc1)
                u32*   __restrict__ flags,        // [4][64] barrier flags
                float* __restrict__ Out)          // [B][T][512] plain
{
    __shared__ float As[KC][34];
    __shared__ float Bs[KC * 64];

    const int tid = threadIdx.x;
    const int bid = blockIdx.x;
    const bool isH = (bid >= 128);
    const int lb  = isH ? (bid - 128) : bid;
    const int mt  = lb >> 5;
    const int nt  = lb & 31;
    const int b0  = mt * 32;
    const int ty  = tid >> 4;
    const int tx  = tid & 15;
    const int r0  = b0 + 2 * ty;
    const int jj  = nt * 16 + tx;

    u32* gf = flags + mt * 64;
    const int wg = (isH ? 32 : 0) + nt;   // id within the 64-block group
    u32 eb = 0;

    const float* Wp = (isH ? WpH : WpX) + (size_t)nt * (KH * 64);

    float creg[2] = {0.f, 0.f}, bv[4] = {0.f, 0.f, 0.f, 0.f};
    if (isH) {
        creg[0] = c0l[(size_t)(r0 + 0) * 1024 + jj];
        creg[1] = c0l[(size_t)(r0 + 1) * 1024 + jj];
        #pragma unroll
        for (int g = 0; g < 4; ++g) bv[g] = bsum[g * 512 + jj];
    }

    // pre-loop: x-blocks produce gx(0) into slot 0
    if (!isH) {
        float acc[2][4] = {};
        gemm_tile<true>(Xin, 0, Wp, acc, As, Bs, b0, tid);
        #pragma unroll
        for (int r = 0; r < 2; ++r) {
            float* q = gx + (size_t)(r0 + r) * G4 + nt * 64 + 4 * tx;
            stc64((u64*)q,       pack2(acc[r][0], acc[r][1]));
            stc64((u64*)(q + 2), pack2(acc[r][2], acc[r][3]));
        }
    }
    ++eb; gbar(gf, eb, wg, tid);

    for (int t = 0; t < T_SEQ; ++t) {
        const int p = t & 1;
        float gv[2][4];

        // ---------------- Phase A ----------------
        if (isH) {
            float acc[2][4] = {};
            gemm_tile<false>(hbuf, 0, Wp, acc, As, Bs, b0, tid);
            const float* gp = gx + (size_t)p * (BB * G4);
            float sa[2][3];
            #pragma unroll
            for (int r = 0; r < 2; ++r) {
                const int b = r0 + r;
                #pragma unroll
                for (int g = 0; g < 4; ++g) {
                    const int col = g * 512 + jj;
                    gv[r][g] = acc[r][g] + ldc(gp + (size_t)b * G4 + col) + bv[g];
                }
                sa[r][0] = fabsf(gv[r][0]);
                sa[r][1] = fabsf(gv[r][1]);
                sa[r][2] = fabsf(gv[r][3]);
            }
            #pragma unroll
            for (int d = 1; d < 16; d <<= 1) {
                #pragma unroll
                for (int r = 0; r < 2; ++r) {
                    sa[r][0] += __shfl_xor(sa[r][0], d, 16);
                    sa[r][1] += __shfl_xor(sa[r][1], d, 16);
                    sa[r][2] += __shfl_xor(sa[r][2], d, 16);
                }
            }
            // store norm partials (single slot; joint barriers order reuse):
            // part[mt][nt][row][4]
            if (tx == 0) {
                float* pw = part + (size_t)((mt * 32 + nt) * 32) * 4;
                #pragma unroll
                for (int r = 0; r < 2; ++r) {
                    const int row = 2 * ty + r;
                    stc(pw + row * 4 + 0, sa[r][0]);
                    stc(pw + row * 4 + 1, sa[r][1]);
                    stc(pw + row * 4 + 2, sa[r][2]);
                }
            }
        } else if (t + 1 < T_SEQ) {
            float acc[2][4] = {};
            gemm_tile<true>(Xin, t + 1, Wp, acc, As, Bs, b0, tid);
            float* gp = gx + (size_t)((t + 1) & 1) * (BB * G4);
            #pragma unroll
            for (int r = 0; r < 2; ++r) {
                float* q = gp + (size_t)(r0 + r) * G4 + nt * 64 + 4 * tx;
                stc64((u64*)q,       pack2(acc[r][0], acc[r][1]));
                stc64((u64*)(q + 2), pack2(acc[r][2], acc[r][3]));
            }
        }
        ++eb; gbar(gf, eb, wg, tid);

        // ---------------- Phase B ----------------
        if (isH) {
            // read partials: lane tx sums blocks nt'=tx and tx+16, butterfly over 16
            float s[2][3];
            {
                const float* pb = part + (size_t)(mt * 32) * 32 * 4;
                #pragma unroll
                for (int r = 0; r < 2; ++r) {
                    const int row = 2 * ty + r;
                    #pragma unroll
                    for (int g = 0; g < 3; ++g)
                        s[r][g] = ldc(pb + ((size_t)tx * 32 + row) * 4 + g)
                                + ldc(pb + ((size_t)(tx + 16) * 32 + row) * 4 + g);
                }
            }
            #pragma unroll
            for (int d = 1; d < 16; d <<= 1) {
                #pragma unroll
                for (int r = 0; r < 2; ++r) {
                    s[r][0] += __shfl_xor(s[r][0], d, 16);
                    s[r][1] += __shfl_xor(s[r][1], d, 16);
                    s[r][2] += __shfl_xor(s[r][2], d, 16);
                }
            }
            #pragma unroll
            for (int r = 0; r < 2; ++r) {
                const int b = r0 + r;
                const float Si = fmaxf(s[r][0], 1e-12f);
                const float Sf = fmaxf(s[r][1], 1e-12f);
                const float So = fmaxf(s[r][2], 1e-12f);
                const float iv = 1.f / (1.f + expf(-gv[r][0] / Si));
                const float fv = 1.f / (1.f + expf(-gv[r][1] / Sf));
                const float ov = 1.f / (1.f + expf(-gv[r][3] / So));
                const float cn = fv * creg[r] + iv * gv[r][2];
                creg[r] = cn;
                const float hn = ov * fmaxf(cn, 0.f);
                stc(hbuf + (size_t)b * 512 + jj, hn);
                Out[((size_t)b * T_SEQ + t) * 512 + jj] = hn;
            }
        }
        ++eb; gbar(gf, eb, wg, tid);
    }
}

// Pack weights: WpX[l][nt][k][c] = Wih[l][nt*64+c][k]
//               WpH[l][nt][k][tx*4+g] = Whh[l][g*512+nt*16+tx][k]
// Also bsum = bih + bhh.
__global__ __launch_bounds__(256)
void pack_w(const float* __restrict__ Wih, const float* __restrict__ Whh,
            const float* __restrict__ bih, const float* __restrict__ bhh,
            float* __restrict__ WpX, float* __restrict__ WpH, float* __restrict__ bsum)
{
    __shared__ float tile[64][65];
    const int tid = threadIdx.x;
    const int blk = blockIdx.x;
    if (blk < 16) bsum[blk * 256 + tid] = bih[blk * 256 + tid] + bhh[blk * 256 + tid];

    const int mat = blk & 1;
    const int kc  = (blk >> 1) & 7;
    const int nt  = (blk >> 4) & 31;
    const int l   = blk >> 9;
    const float* W = mat ? Whh : Wih;
    float* Wp = mat ? WpH : WpX;

    const int c  = tid >> 2;
    const int ko = (tid & 3) * 16;
    const int grow = mat ? ((c & 3) * 512 + nt * 16 + (c >> 2))
                         : (nt * 64 + c);
    const float* src = W + ((size_t)(l * G4 + grow)) * 512 + kc * 64 + ko;
    #pragma unroll
    for (int it = 0; it < 4; ++it) {
        float4 v = ((const float4*)src)[it];
        tile[c][ko + 4*it + 0] = v.x;
        tile[c][ko + 4*it + 1] = v.y;
        tile[c][ko + 4*it + 2] = v.z;
        tile[c][ko + 4*it + 3] = v.w;
    }
    __syncthreads();
    const int k  = tid >> 2;
    const int co = (tid & 3) * 16;
    float* dst = Wp + ((size_t)((l * 32 + nt) * 512) + kc * 64 + k) * 64 + co;
    #pragma unroll
    for (int it = 0; it < 4; ++it) {
        float4 v;
        v.x = tile[co + 4*it + 0][k];
        v.y = tile[co + 4*it + 1][k];
        v.z = tile[co + 4*it + 2][k];
        v.w = tile[co + 4*it + 3][k];
        ((float4*)dst)[it] = v;
    }
}

__global__ __launch_bounds__(256)
void init_layer(const float* __restrict__ h0l, float* __restrict__ hbuf,
                u32* __restrict__ flags)
{
    const int idx = blockIdx.x * blockDim.x + threadIdx.x;
    if (idx < 1024) flags[idx] = 0u;
    if (idx < BB * HH) {
        const int b = idx >> 9, j = idx & 511;
        hbuf[idx] = h0l[(size_t)b * 1024 + j];
    }
}

extern "C" void kernel_launch(void* const* d_in, const int* in_sizes, int n_in,
                              void* d_out, int out_size, void* d_ws, size_t ws_size,
                              hipStream_t stream)
{
    const float* x   = (const float*)d_in[0];
    const float* h0  = (const float*)d_in[1];
    const float* c0  = (const float*)d_in[2];
    const float* Wih = (const float*)d_in[3];
    const float* bih = (const float*)d_in[4];
    const float* Whh = (const float*)d_in[5];
    const float* bhh = (const float*)d_in[6];
    float* out = (float*)d_out;
    float* ws  = (float*)d_ws;

    // ws layout (floats), total ~18.3 MB
    u32*   flags = (u32*)ws;                   // 1024 u32
    float* part  = ws + 1024;                  // 4*32*32*4 = 16384
    float* hbuf  = part + 16384;               // 65536
    float* gx    = hbuf + BB * HH;             // 2*128*2048 = 524288
    float* WpX   = gx + 2 * BB * G4;           // 2097152
    float* WpH   = WpX + 2 * 32 * 512 * 64;    // 2097152
    float* bsum  = WpH + 2 * 32 * 512 * 64;    // 4096

    hipLaunchKernelGGL(pack_w, dim3(1024), dim3(256), 0, stream,
                       Wih, Whh, bih, bhh, WpX, WpH, bsum);

    for (int l = 0; l < 2; ++l) {
        hipLaunchKernelGGL(init_layer, dim3(256), dim3(256), 0, stream,
                           h0 + l * 512, hbuf, flags);
        const float* Xin  = (l == 0) ? x : (const float*)out;
        const float* WpXl = WpX + (size_t)l * 32 * 512 * 64;
        const float* WpHl = WpH + (size_t)l * 32 * 512 * 64;
        const float* bsl  = bsum + l * 2048;
        const float* c0l  = c0 + l * 512;
        void* args[] = {(void*)&Xin, (void*)&WpXl, (void*)&WpHl, (void*)&bsl, (void*)&c0l,
                        (void*)&hbuf, (void*)&gx, (void*)&part, (void*)&flags, (void*)&out};
        hipLaunchCooperativeKernel(reinterpret_cast<void*>(lstm_layer),
                                   dim3(NBLK), dim3(NTHR), args, 0, stream);
    }
}

// Round 8
// 40756.769 us; speedup vs baseline: 3.4679x; 1.1222x over previous
//
#include <hip/hip_runtime.h>

#define T_SEQ 512
#define BB    128
#define HH    512
#define G4    2048
#define KH    512
#define NBLK  256
#define NTHR  256
#define KC    64
#define NCHUNK (KH / KC)   // 8

#define SCOPE __HIP_MEMORY_SCOPE_AGENT

typedef unsigned long long u64;
typedef unsigned u32;
typedef unsigned short u16;

__device__ __forceinline__ float ldc(const float* p) {
    return __hip_atomic_load(p, __ATOMIC_RELAXED, SCOPE);
}
__device__ __forceinline__ void stc(float* p, float v) {
    __hip_atomic_store(p, v, __ATOMIC_RELAXED, SCOPE);
}
__device__ __forceinline__ u64 ldc64(const u64* p) {
    return __hip_atomic_load(p, __ATOMIC_RELAXED, SCOPE);
}
__device__ __forceinline__ void stc64(u64* p, u64 v) {
    __hip_atomic_store(p, v, __ATOMIC_RELAXED, SCOPE);
}
__device__ __forceinline__ u32 ldcu(const u32* p) {
    return __hip_atomic_load(p, __ATOMIC_RELAXED, SCOPE);
}
__device__ __forceinline__ void stcu(u32* p, u32 v) {
    __hip_atomic_store(p, v, __ATOMIC_RELAXED, SCOPE);
}
__device__ __forceinline__ u64 pack2(float a, float b) {
    union { float f[2]; u64 u; } x; x.f[0] = a; x.f[1] = b; return x.u;
}
__device__ __forceinline__ float2 unpack2(u64 v) {
    union { u64 u; float2 f; } x; x.u = v; return x.f;
}
// bf16 (stored packed 2-per-u32, little-endian) -> fp32
__device__ __forceinline__ float blo(u32 w) {
    union { u32 u; float f; } t; t.u = w << 16; return t.f;
}
__device__ __forceinline__ float bhi(u32 w) {
    union { u32 u; float f; } t; t.u = w & 0xFFFF0000u; return t.f;
}
// fp32 -> bf16 bits, round-to-nearest-even
__device__ __forceinline__ u16 f2b(float f) {
    union { float f; u32 u; } t; t.f = f;
    u32 r = (t.u + 0x7FFFu + ((t.u >> 16) & 1u)) >> 16;
    return (u16)r;
}

// Per-mt-group joint barrier, NO RMW: arrival = one flag store (own slot),
// detection = wave 0 loads all 64 flags in parallel + __all ballot.
// Flags are monotonic epochs, zeroed per launch by init_layer.
__device__ __forceinline__ void gbar(u32* gf, u32 e, int wg, int tid) {
    asm volatile("s_waitcnt vmcnt(0)" ::: "memory");  // drain this wave's stores
    __syncthreads();
    if (tid == 0) stcu(gf + wg, e);
    if (tid < 64) {
        const u32* p = gf + tid;
        for (;;) {
            u32 v = ldcu(p);
            if (__all((int)(v - e) >= 0)) break;
            __builtin_amdgcn_s_sleep(1);
        }
    }
    __syncthreads();
    asm volatile("" ::: "memory");
}

// Tiled GEMM for one 32x64 tile, K=512, acc 2 rows x 4 cols per thread.
// XPATH: A = Xin[b][tt][:] (plain fp32 loads).  !XPATH: A = hbuf (sc1 fp32).
// B = packed bf16 weights (plain cached loads, L2-resident: 2 MB/XCD),
// converted to fp32 at LDS-staging time; inner loop is unchanged fp32 FMA.
template<bool XPATH>
__device__ __forceinline__ void gemm_tile(
    const float* __restrict__ Asrc, int tt,
    const u16* __restrict__ Wp,
    float acc[2][4],
    float (*As)[34], float* Bs,
    int b0, int tid)
{
    const int sr8 = tid >> 5;      // h staging: row 0..7
    const int sc2 = tid & 31;      // h staging: k-pair
    const int xr  = tid >> 4;      // x staging: row 0..15
    const int xc4 = tid & 15;      // x staging: k-quad
    const int ty  = tid >> 4;
    const int tx  = tid & 15;

    u64   vaH[2][4];
    float4 vaX[2][2];
    uint4  vb16[2];

    auto loadA = [&](int c, int s) {
        if (XPATH) {
            #pragma unroll
            for (int it = 0; it < 2; ++it) {
                const float* p = Asrc + ((size_t)(b0 + xr + 16*it) * T_SEQ + tt) * 512
                                 + c * KC + 4 * xc4;
                vaX[s][it] = *(const float4*)p;
            }
        } else {
            #pragma unroll
            for (int it = 0; it < 4; ++it) {
                const float* p = Asrc + (size_t)(b0 + sr8 + 8*it) * 512 + c * KC + 2 * sc2;
                vaH[s][it] = ldc64((const u64*)p);
            }
        }
    };
    auto loadB = [&](int c) {
        // chunk = KC*64 = 4096 bf16 = 512 uint4; thread tid takes groups
        // {tid, tid+256} = elements [8t..8t+7], [2048+8t..2048+8t+7]
        const uint4* p = (const uint4*)(Wp + (size_t)c * (KC * 64));
        vb16[0] = p[tid];
        vb16[1] = p[tid + 256];
    };
    auto writeLDS = [&](int s) {
        if (XPATH) {
            #pragma unroll
            for (int it = 0; it < 2; ++it) {
                As[4*xc4+0][xr+16*it] = vaX[s][it].x;
                As[4*xc4+1][xr+16*it] = vaX[s][it].y;
                As[4*xc4+2][xr+16*it] = vaX[s][it].z;
                As[4*xc4+3][xr+16*it] = vaX[s][it].w;
            }
        } else {
            #pragma unroll
            for (int it = 0; it < 4; ++it) {
                float2 f = unpack2(vaH[s][it]);
                As[2*sc2+0][sr8+8*it] = f.x;
                As[2*sc2+1][sr8+8*it] = f.y;
            }
        }
        // convert 16 bf16 -> 16 fp32, straight copy into Bs (same linear layout)
        #pragma unroll
        for (int it = 0; it < 2; ++it) {
            const uint4 w = vb16[it];
            float* q = Bs + 2048 * it + 8 * tid;
            *(float4*)(q)     = make_float4(blo(w.x), bhi(w.x), blo(w.y), bhi(w.y));
            *(float4*)(q + 4) = make_float4(blo(w.z), bhi(w.z), blo(w.w), bhi(w.w));
        }
    };

    loadA(0, 0);
    loadB(0);
    loadA(1, 1);
    for (int c = 0; c < NCHUNK; ++c) {
        __syncthreads();
        writeLDS(c & 1);
        __syncthreads();
        if (c + 2 < NCHUNK) loadA(c + 2, c & 1);
        if (c + 1 < NCHUNK) loadB(c + 1);
        #pragma unroll
        for (int kk = 0; kk < KC; ++kk) {
            float2 a = *(const float2*)&As[kk][2 * ty];
            float4 b = *(const float4*)&Bs[kk * 64 + 4 * tx];
            acc[0][0] = fmaf(a.x, b.x, acc[0][0]);
            acc[0][1] = fmaf(a.x, b.y, acc[0][1]);
            acc[0][2] = fmaf(a.x, b.z, acc[0][2]);
            acc[0][3] = fmaf(a.x, b.w, acc[0][3]);
            acc[1][0] = fmaf(a.y, b.x, acc[1][0]);
            acc[1][1] = fmaf(a.y, b.y, acc[1][1]);
            acc[1][2] = fmaf(a.y, b.z, acc[1][2]);
            acc[1][3] = fmaf(a.y, b.w, acc[1][3]);
        }
    }
}

// One layer, persistent cooperative kernel, per-mt-group joint barriers (flag-based).
// Blocks 0..127   : x-blocks (mt,nt), compute gx(t+1) = Wih @ x_{t+1} (one step ahead)
// Blocks 128..255 : h-blocks (mt,nt), compute gh(t) = Whh @ h_t, gates in regs,
//                   c-state in regs, L1-norms via shfl + partial stores (no atomics).
__global__ __launch_bounds__(NTHR)
void lstm_layer(const float* __restrict__ Xin,
                const u16* __restrict__ WpX,      // packed bf16 Wih
                const u16* __restrict__ WpH,      // packed bf16 Whh
                const float* __restrict__ bsum,   // bih+bhh [2048]
                const float* __restrict__ c0l,    // c0 + l*512, idx b*1024+j
                float* __restrict__ hbuf,         // [128*512]        (sc1)
                float* __restrict__ gx,           // [2][128*2048]    (sc1)
                float* __restrict__ part,         // [4][32][32][4]   (sc1)
                u32*   __restrict__ flags,        // [4][64] barrier flags
                float* __restrict__ Out)          // [B][T][512] plain
{
    __shared__ float As[KC][34];
    __shared__ float Bs[KC * 64];

    const int tid = threadIdx.x;
    const int bid = blockIdx.x;
    const bool isH = (bid >= 128);
    const int lb  = isH ? (bid - 128) : bid;
    const int mt  = lb >> 5;
    const int nt  = lb & 31;
    const int b0  = mt * 32;
    const int ty  = tid >> 4;
    const int tx  = tid & 15;
    const int r0  = b0 + 2 * ty;
    const int jj  = nt * 16 + tx;

    u32* gf = flags + mt * 64;
    const int wg = (isH ? 32 : 0) + nt;   // id within the 64-block group
    u32 eb = 0;

    const u16* Wp = (isH ? WpH : WpX) + (size_t)nt * (KH * 64);

    float creg[2] = {0.f, 0.f}, bv[4] = {0.f, 0.f, 0.f, 0.f};
    if (isH) {
        creg[0] = c0l[(size_t)(r0 + 0) * 1024 + jj];
        creg[1] = c0l[(size_t)(r0 + 1) * 1024 + jj];
        #pragma unroll
        for (int g = 0; g < 4; ++g) bv[g] = bsum[g * 512 + jj];
    }

    // pre-loop: x-blocks produce gx(0) into slot 0
    if (!isH) {
        float acc[2][4] = {};
        gemm_tile<true>(Xin, 0, Wp, acc, As, Bs, b0, tid);
        #pragma unroll
        for (int r = 0; r < 2; ++r) {
            float* q = gx + (size_t)(r0 + r) * G4 + nt * 64 + 4 * tx;
            stc64((u64*)q,       pack2(acc[r][0], acc[r][1]));
            stc64((u64*)(q + 2), pack2(acc[r][2], acc[r][3]));
        }
    }
    ++eb; gbar(gf, eb, wg, tid);

    for (int t = 0; t < T_SEQ; ++t) {
        const int p = t & 1;
        float gv[2][4];

        // ---------------- Phase A ----------------
        if (isH) {
            float acc[2][4] = {};
            gemm_tile<false>(hbuf, 0, Wp, acc, As, Bs, b0, tid);
            const float* gp = gx + (size_t)p * (BB * G4);
            float sa[2][3];
            #pragma unroll
            for (int r = 0; r < 2; ++r) {
                const int b = r0 + r;
                #pragma unroll
                for (int g = 0; g < 4; ++g) {
                    const int col = g * 512 + jj;
                    gv[r][g] = acc[r][g] + ldc(gp + (size_t)b * G4 + col) + bv[g];
                }
                sa[r][0] = fabsf(gv[r][0]);
                sa[r][1] = fabsf(gv[r][1]);
                sa[r][2] = fabsf(gv[r][3]);
            }
            #pragma unroll
            for (int d = 1; d < 16; d <<= 1) {
                #pragma unroll
                for (int r = 0; r < 2; ++r) {
                    sa[r][0] += __shfl_xor(sa[r][0], d, 16);
                    sa[r][1] += __shfl_xor(sa[r][1], d, 16);
                    sa[r][2] += __shfl_xor(sa[r][2], d, 16);
                }
            }
            // store norm partials (single slot; joint barriers order reuse):
            // part[mt][nt][row][4]
            if (tx == 0) {
                float* pw = part + (size_t)((mt * 32 + nt) * 32) * 4;
                #pragma unroll
                for (int r = 0; r < 2; ++r) {
                    const int row = 2 * ty + r;
                    stc(pw + row * 4 + 0, sa[r][0]);
                    stc(pw + row * 4 + 1, sa[r][1]);
                    stc(pw + row * 4 + 2, sa[r][2]);
                }
            }
        } else if (t + 1 < T_SEQ) {
            float acc[2][4] = {};
            gemm_tile<true>(Xin, t + 1, Wp, acc, As, Bs, b0, tid);
            float* gp = gx + (size_t)((t + 1) & 1) * (BB * G4);
            #pragma unroll
            for (int r = 0; r < 2; ++r) {
                float* q = gp + (size_t)(r0 + r) * G4 + nt * 64 + 4 * tx;
                stc64((u64*)q,       pack2(acc[r][0], acc[r][1]));
                stc64((u64*)(q + 2), pack2(acc[r][2], acc[r][3]));
            }
        }
        ++eb; gbar(gf, eb, wg, tid);

        // ---------------- Phase B ----------------
        if (isH) {
            // read partials: lane tx sums blocks nt'=tx and tx+16, butterfly over 16
            float s[2][3];
            {
                const float* pb = part + (size_t)(mt * 32) * 32 * 4;
                #pragma unroll
                for (int r = 0; r < 2; ++r) {
                    const int row = 2 * ty + r;
                    #pragma unroll
                    for (int g = 0; g < 3; ++g)
                        s[r][g] = ldc(pb + ((size_t)tx * 32 + row) * 4 + g)
                                + ldc(pb + ((size_t)(tx + 16) * 32 + row) * 4 + g);
                }
            }
            #pragma unroll
            for (int d = 1; d < 16; d <<= 1) {
                #pragma unroll
                for (int r = 0; r < 2; ++r) {
                    s[r][0] += __shfl_xor(s[r][0], d, 16);
                    s[r][1] += __shfl_xor(s[r][1], d, 16);
                    s[r][2] += __shfl_xor(s[r][2], d, 16);
                }
            }
            #pragma unroll
            for (int r = 0; r < 2; ++r) {
                const int b = r0 + r;
                const float Si = fmaxf(s[r][0], 1e-12f);
                const float Sf = fmaxf(s[r][1], 1e-12f);
                const float So = fmaxf(s[r][2], 1e-12f);
                const float iv = 1.f / (1.f + expf(-gv[r][0] / Si));
                const float fv = 1.f / (1.f + expf(-gv[r][1] / Sf));
                const float ov = 1.f / (1.f + expf(-gv[r][3] / So));
                const float cn = fv * creg[r] + iv * gv[r][2];
                creg[r] = cn;
                const float hn = ov * fmaxf(cn, 0.f);
                stc(hbuf + (size_t)b * 512 + jj, hn);
                Out[((size_t)b * T_SEQ + t) * 512 + jj] = hn;
            }
        }
        ++eb; gbar(gf, eb, wg, tid);
    }
}

// Pack weights to bf16, both matrices gate-interleaved layout:
//   WpX[l][nt][k][c] = bf16( Wih[l][nt*64+c][k] )
//   WpH[l][nt][k][c] = bf16( Whh[l][(c&3)*512+nt*16+(c>>2)][k] )
// Also bsum = bih + bhh (fp32).
__global__ __launch_bounds__(256)
void pack_w(const float* __restrict__ Wih, const float* __restrict__ Whh,
            const float* __restrict__ bih, const float* __restrict__ bhh,
            u16* __restrict__ WpX, u16* __restrict__ WpH, float* __restrict__ bsum)
{
    __shared__ float tile[64][65];
    const int tid = threadIdx.x;
    const int blk = blockIdx.x;
    if (blk < 16) bsum[blk * 256 + tid] = bih[blk * 256 + tid] + bhh[blk * 256 + tid];

    const int mat = blk & 1;
    const int kc  = (blk >> 1) & 7;
    const int nt  = (blk >> 4) & 31;
    const int l   = blk >> 9;
    const float* W = mat ? Whh : Wih;
    u16* Wp = mat ? WpH : WpX;

    const int c  = tid >> 2;
    const int ko = (tid & 3) * 16;
    const int grow = mat ? ((c & 3) * 512 + nt * 16 + (c >> 2))
                         : (nt * 64 + c);
    const float* src = W + ((size_t)(l * G4 + grow)) * 512 + kc * 64 + ko;
    #pragma unroll
    for (int it = 0; it < 4; ++it) {
        float4 v = ((const float4*)src)[it];
        tile[c][ko + 4*it + 0] = v.x;
        tile[c][ko + 4*it + 1] = v.y;
        tile[c][ko + 4*it + 2] = v.z;
        tile[c][ko + 4*it + 3] = v.w;
    }
    __syncthreads();
    const int k  = tid >> 2;
    const int co = (tid & 3) * 16;
    u16* dst = Wp + ((size_t)((l * 32 + nt) * 512) + kc * 64 + k) * 64 + co;
    #pragma unroll
    for (int it = 0; it < 4; ++it) {
        const u64 w = (u64)f2b(tile[co + 4*it + 0][k])
                    | ((u64)f2b(tile[co + 4*it + 1][k]) << 16)
                    | ((u64)f2b(tile[co + 4*it + 2][k]) << 32)
                    | ((u64)f2b(tile[co + 4*it + 3][k]) << 48);
        *(u64*)(dst + 4 * it) = w;
    }
}

__global__ __launch_bounds__(256)
void init_layer(const float* __restrict__ h0l, float* __restrict__ hbuf,
                u32* __restrict__ flags)
{
    const int idx = blockIdx.x * blockDim.x + threadIdx.x;
    if (idx < 1024) flags[idx] = 0u;
    if (idx < BB * HH) {
        const int b = idx >> 9, j = idx & 511;
        hbuf[idx] = h0l[(size_t)b * 1024 + j];
    }
}

extern "C" void kernel_launch(void* const* d_in, const int* in_sizes, int n_in,
                              void* d_out, int out_size, void* d_ws, size_t ws_size,
                              hipStream_t stream)
{
    const float* x   = (const float*)d_in[0];
    const float* h0  = (const float*)d_in[1];
    const float* c0  = (const float*)d_in[2];
    const float* Wih = (const float*)d_in[3];
    const float* bih = (const float*)d_in[4];
    const float* Whh = (const float*)d_in[5];
    const float* bhh = (const float*)d_in[6];
    float* out = (float*)d_out;
    float* ws  = (float*)d_ws;

    // ws layout, total ~10.4 MB (bf16 weights)
    u32*   flags = (u32*)ws;                    // 1024 u32
    float* part  = ws + 1024;                   // 4*32*32*4 = 16384 floats
    float* hbuf  = part + 16384;                // 65536 floats
    float* gx    = hbuf + BB * HH;              // 2*128*2048 = 524288 floats
    u16*   WpX   = (u16*)(gx + 524288);         // 2*1048576 bf16
    u16*   WpH   = WpX + 2 * 1048576;           // 2*1048576 bf16
    float* bsum  = (float*)(WpH + 2 * 1048576); // 4096 floats

    hipLaunchKernelGGL(pack_w, dim3(1024), dim3(256), 0, stream,
                       Wih, Whh, bih, bhh, WpX, WpH, bsum);

    for (int l = 0; l < 2; ++l) {
        hipLaunchKernelGGL(init_layer, dim3(256), dim3(256), 0, stream,
                           h0 + l * 512, hbuf, flags);
        const float* Xin  = (l == 0) ? x : (const float*)out;
        const u16*   WpXl = WpX + (size_t)l * 1048576;
        const u16*   WpHl = WpH + (size_t)l * 1048576;
        const float* bsl  = bsum + l * 2048;
        const float* c0l  = c0 + l * 512;
        void* args[] = {(void*)&Xin, (void*)&WpXl, (void*)&WpHl, (void*)&bsl, (void*)&c0l,
                        (void*)&hbuf, (void*)&gx, (void*)&part, (void*)&flags, (void*)&out};
        hipLaunchCooperativeKernel(reinterpret_cast<void*>(lstm_layer),
                                   dim3(NBLK), dim3(NTHR), args, 0, stream);
    }
}

// Round 10
// 35047.394 us; speedup vs baseline: 4.0328x; 1.1629x over previous
//
#include <hip/hip_runtime.h>

#define T_SEQ 512
#define BB    128
#define HH    512
#define G4    2048
#define KH    512
#define NBLK  256
#define NTHR  256
#define KC    64
#define NCHUNK (KH / KC)   // 8
#define KP    32           // k-pairs per chunk

#define SCOPE __HIP_MEMORY_SCOPE_AGENT

typedef unsigned long long u64;
typedef unsigned u32;
typedef unsigned short u16;
typedef __fp16 half2v __attribute__((ext_vector_type(2)));

__device__ __forceinline__ float ldc(const float* p) {
    return __hip_atomic_load(p, __ATOMIC_RELAXED, SCOPE);
}
__device__ __forceinline__ void stc(float* p, float v) {
    __hip_atomic_store(p, v, __ATOMIC_RELAXED, SCOPE);
}
__device__ __forceinline__ u64 ldc64(const u64* p) {
    return __hip_atomic_load(p, __ATOMIC_RELAXED, SCOPE);
}
__device__ __forceinline__ void stc64(u64* p, u64 v) {
    __hip_atomic_store(p, v, __ATOMIC_RELAXED, SCOPE);
}
__device__ __forceinline__ u32 ldcu(const u32* p) {
    return __hip_atomic_load(p, __ATOMIC_RELAXED, SCOPE);
}
__device__ __forceinline__ void stcu(u32* p, u32 v) {
    __hip_atomic_store(p, v, __ATOMIC_RELAXED, SCOPE);
}
__device__ __forceinline__ u64 pack2(float a, float b) {
    union { float f[2]; u64 u; } x; x.f[0] = a; x.f[1] = b; return x.u;
}
__device__ __forceinline__ float2 unpack2(u64 v) {
    union { u64 u; float2 f; } x; x.u = v; return x.f;
}
// pack two fp32 -> packed f16 pair (u32), round-toward-zero (v_cvt_pkrtz)
__device__ __forceinline__ u32 pk2(float a, float b) {
    union { half2v h; u32 u; } t;
    t.h = __builtin_amdgcn_cvt_pkrtz(a, b);
    return t.u;
}
// packed-f16 dot2 with fp32 accumulate
__device__ __forceinline__ float dot2(u32 a, u32 b, float c) {
    union { u32 u; half2v h; } x, y;
    x.u = a; y.u = b;
#if __has_builtin(__builtin_amdgcn_fdot2)
    return __builtin_amdgcn_fdot2(x.h, y.h, c, false);
#else
    return c + (float)x.h.x * (float)y.h.x + (float)x.h.y * (float)y.h.y;
#endif
}

// Per-mt-group joint barrier, NO RMW: arrival = one flag store (own slot),
// detection = wave 0 loads all 64 flags in parallel + __all ballot.
__device__ __forceinline__ void gbar(u32* gf, u32 e, int wg, int tid) {
    asm volatile("s_waitcnt vmcnt(0)" ::: "memory");  // drain this wave's stores
    __syncthreads();
    if (tid == 0) stcu(gf + wg, e);
    if (tid < 64) {
        const u32* p = gf + tid;
        for (;;) {
            u32 v = ldcu(p);
            if (__all((int)(v - e) >= 0)) break;
            __builtin_amdgcn_s_sleep(1);
        }
    }
    __syncthreads();
    asm volatile("" ::: "memory");
}

// Tiled GEMM for one 32x64 tile, K=512, acc 2 rows x 4 cols per thread.
// Operands in LDS as packed f16 k-pairs; inner loop = 32 kp x 8 dot2.
// XPATH: A = Xin[b][tt][:] (plain fp32, packed at staging).
// !XPATH: A = hbuf (sc1 fp32, packed at staging).
// B = f16-packed weights (plain cached loads, raw-copied to LDS).
template<bool XPATH>
__device__ __forceinline__ void gemm_tile(
    const float* __restrict__ Asrc, int tt,
    const u32* __restrict__ Wp,
    float acc[2][4],
    u32 (*As2)[34], u32* Bs,
    int b0, int tid)
{
    const int sr8 = tid >> 5;      // h staging: row 0..7
    const int sc2 = tid & 31;      // h staging: k-pair 0..31
    const int xr  = tid >> 4;      // x staging: row 0..15
    const int xc4 = tid & 15;      // x staging: k-quad
    const int ty  = tid >> 4;
    const int tx  = tid & 15;

    u64   vaH[2][4];
    float4 vaX[2][2];
    uint4  vb16[2];

    auto loadA = [&](int c, int s) {
        if (XPATH) {
            #pragma unroll
            for (int it = 0; it < 2; ++it) {
                const float* p = Asrc + ((size_t)(b0 + xr + 16*it) * T_SEQ + tt) * 512
                                 + c * KC + 4 * xc4;
                vaX[s][it] = *(const float4*)p;
            }
        } else {
            #pragma unroll
            for (int it = 0; it < 4; ++it) {
                const float* p = Asrc + (size_t)(b0 + sr8 + 8*it) * 512 + c * KC + 2 * sc2;
                vaH[s][it] = ldc64((const u64*)p);
            }
        }
    };
    auto loadB = [&](int c) {
        // chunk = KP*64 = 2048 u32 (f16 pairs) = 512 uint4
        const uint4* p = (const uint4*)(Wp + (size_t)c * (KP * 64));
        vb16[0] = p[tid];
        vb16[1] = p[tid + 256];
    };
    auto writeLDS = [&](int s) {
        if (XPATH) {
            #pragma unroll
            for (int it = 0; it < 2; ++it) {
                const float4 v = vaX[s][it];
                As2[2*xc4+0][xr+16*it] = pk2(v.x, v.y);
                As2[2*xc4+1][xr+16*it] = pk2(v.z, v.w);
            }
        } else {
            #pragma unroll
            for (int it = 0; it < 4; ++it) {
                float2 f = unpack2(vaH[s][it]);
                As2[sc2][sr8+8*it] = pk2(f.x, f.y);
            }
        }
        ((uint4*)Bs)[tid]       = vb16[0];
        ((uint4*)Bs)[tid + 256] = vb16[1];
    };

    loadA(0, 0);
    loadB(0);
    loadA(1, 1);
    for (int c = 0; c < NCHUNK; ++c) {
        __syncthreads();
        writeLDS(c & 1);
        __syncthreads();
        if (c + 2 < NCHUNK) loadA(c + 2, c & 1);
        if (c + 1 < NCHUNK) loadB(c + 1);
        #pragma unroll
        for (int kp = 0; kp < KP; ++kp) {
            uint2 a = *(const uint2*)&As2[kp][2 * ty];
            uint4 b = *(const uint4*)&Bs[kp * 64 + 4 * tx];
            acc[0][0] = dot2(a.x, b.x, acc[0][0]);
            acc[0][1] = dot2(a.x, b.y, acc[0][1]);
            acc[0][2] = dot2(a.x, b.z, acc[0][2]);
            acc[0][3] = dot2(a.x, b.w, acc[0][3]);
            acc[1][0] = dot2(a.y, b.x, acc[1][0]);
            acc[1][1] = dot2(a.y, b.y, acc[1][1]);
            acc[1][2] = dot2(a.y, b.z, acc[1][2]);
            acc[1][3] = dot2(a.y, b.w, acc[1][3]);
        }
    }
}

// One layer, persistent cooperative kernel, per-mt-group joint barriers (flag-based).
// Blocks 0..127   : x-blocks (mt,nt), compute gx(t+1) = Wih @ x_{t+1} (one step ahead)
// Blocks 128..255 : h-blocks (mt,nt), compute gh(t) = Whh @ h_t, gates in regs,
//                   c-state in regs, L1-norms via shfl + partial stores (no atomics).
__global__ __launch_bounds__(NTHR)
void lstm_layer(const float* __restrict__ Xin,
                const u32* __restrict__ WpX,      // packed f16-pair Wih
                const u32* __restrict__ WpH,      // packed f16-pair Whh
                const float* __restrict__ bsum,   // bih+bhh [2048]
                const float* __restrict__ c0l,    // c0 + l*512, idx b*1024+j
                float* __restrict__ hbuf,         // [128*512]        (sc1)
                float* __restrict__ gx,           // [2][128*2048]    (sc1)
                float* __restrict__ part,         // [4][32][32][4]   (sc1)
                u32*   __restrict__ flags,        // [4][64] barrier flags
                float* __restrict__ Out)          // [B][T][512] plain
{
    __shared__ u32 As2[KP][34];
    __shared__ u32 Bs[KP * 64];

    const int tid = threadIdx.x;
    const int bid = blockIdx.x;
    const bool isH = (bid >= 128);
    const int lb  = isH ? (bid - 128) : bid;
    const int mt  = lb >> 5;
    const int nt  = lb & 31;
    const int b0  = mt * 32;
    const int ty  = tid >> 4;
    const int tx  = tid & 15;
    const int r0  = b0 + 2 * ty;
    const int jj  = nt * 16 + tx;

    u32* gf = flags + mt * 64;
    const int wg = (isH ? 32 : 0) + nt;   // id within the 64-block group
    u32 eb = 0;

    const u32* Wp = (isH ? WpH : WpX) + (size_t)nt * (256 * 64);

    float creg[2] = {0.f, 0.f}, bv[4] = {0.f, 0.f, 0.f, 0.f};
    if (isH) {
        creg[0] = c0l[(size_t)(r0 + 0) * 1024 + jj];
        creg[1] = c0l[(size_t)(r0 + 1) * 1024 + jj];
        #pragma unroll
        for (int g = 0; g < 4; ++g) bv[g] = bsum[g * 512 + jj];
    }

    // pre-loop: x-blocks produce gx(0) into slot 0
    if (!isH) {
        float acc[2][4] = {};
        gemm_tile<true>(Xin, 0, Wp, acc, As2, Bs, b0, tid);
        #pragma unroll
        for (int r = 0; r < 2; ++r) {
            float* q = gx + (size_t)(r0 + r) * G4 + nt * 64 + 4 * tx;
            stc64((u64*)q,       pack2(acc[r][0], acc[r][1]));
            stc64((u64*)(q + 2), pack2(acc[r][2], acc[r][3]));
        }
    }
    ++eb; gbar(gf, eb, wg, tid);

    for (int t = 0; t < T_SEQ; ++t) {
        const int p = t & 1;
        float gv[2][4];

        // ---------------- Phase A ----------------
        if (isH) {
            float acc[2][4] = {};
            gemm_tile<false>(hbuf, 0, Wp, acc, As2, Bs, b0, tid);
            const float* gp = gx + (size_t)p * (BB * G4);
            float sa[2][3];
            #pragma unroll
            for (int r = 0; r < 2; ++r) {
                const int b = r0 + r;
                #pragma unroll
                for (int g = 0; g < 4; ++g) {
                    const int col = g * 512 + jj;
                    gv[r][g] = acc[r][g] + ldc(gp + (size_t)b * G4 + col) + bv[g];
                }
                sa[r][0] = fabsf(gv[r][0]);
                sa[r][1] = fabsf(gv[r][1]);
                sa[r][2] = fabsf(gv[r][3]);
            }
            #pragma unroll
            for (int d = 1; d < 16; d <<= 1) {
                #pragma unroll
                for (int r = 0; r < 2; ++r) {
                    sa[r][0] += __shfl_xor(sa[r][0], d, 16);
                    sa[r][1] += __shfl_xor(sa[r][1], d, 16);
                    sa[r][2] += __shfl_xor(sa[r][2], d, 16);
                }
            }
            // store norm partials (single slot; joint barriers order reuse):
            // part[mt][nt][row][4]
            if (tx == 0) {
                float* pw = part + (size_t)((mt * 32 + nt) * 32) * 4;
                #pragma unroll
                for (int r = 0; r < 2; ++r) {
                    const int row = 2 * ty + r;
                    stc(pw + row * 4 + 0, sa[r][0]);
                    stc(pw + row * 4 + 1, sa[r][1]);
                    stc(pw + row * 4 + 2, sa[r][2]);
                }
            }
        } else if (t + 1 < T_SEQ) {
            float acc[2][4] = {};
            gemm_tile<true>(Xin, t + 1, Wp, acc, As2, Bs, b0, tid);
            float* gp = gx + (size_t)((t + 1) & 1) * (BB * G4);
            #pragma unroll
            for (int r = 0; r < 2; ++r) {
                float* q = gp + (size_t)(r0 + r) * G4 + nt * 64 + 4 * tx;
                stc64((u64*)q,       pack2(acc[r][0], acc[r][1]));
                stc64((u64*)(q + 2), pack2(acc[r][2], acc[r][3]));
            }
        }
        ++eb; gbar(gf, eb, wg, tid);

        // ---------------- Phase B ----------------
        if (isH) {
            // read partials: lane tx sums blocks nt'=tx and tx+16, butterfly over 16
            float s[2][3];
            {
                const float* pb = part + (size_t)(mt * 32) * 32 * 4;
                #pragma unroll
                for (int r = 0; r < 2; ++r) {
                    const int row = 2 * ty + r;
                    #pragma unroll
                    for (int g = 0; g < 3; ++g)
                        s[r][g] = ldc(pb + ((size_t)tx * 32 + row) * 4 + g)
                                + ldc(pb + ((size_t)(tx + 16) * 32 + row) * 4 + g);
                }
            }
            #pragma unroll
            for (int d = 1; d < 16; d <<= 1) {
                #pragma unroll
                for (int r = 0; r < 2; ++r) {
                    s[r][0] += __shfl_xor(s[r][0], d, 16);
                    s[r][1] += __shfl_xor(s[r][1], d, 16);
                    s[r][2] += __shfl_xor(s[r][2], d, 16);
                }
            }
            #pragma unroll
            for (int r = 0; r < 2; ++r) {
                const int b = r0 + r;
                const float Si = fmaxf(s[r][0], 1e-12f);
                const float Sf = fmaxf(s[r][1], 1e-12f);
                const float So = fmaxf(s[r][2], 1e-12f);
                const float iv = 1.f / (1.f + expf(-gv[r][0] / Si));
                const float fv = 1.f / (1.f + expf(-gv[r][1] / Sf));
                const float ov = 1.f / (1.f + expf(-gv[r][3] / So));
                const float cn = fv * creg[r] + iv * gv[r][2];
                creg[r] = cn;
                const float hn = ov * fmaxf(cn, 0.f);
                stc(hbuf + (size_t)b * 512 + jj, hn);
                Out[((size_t)b * T_SEQ + t) * 512 + jj] = hn;
            }
        }
        ++eb; gbar(gf, eb, wg, tid);
    }
}

// Pack weights to f16 k-pairs, gate-interleaved layout:
//   Wp_u32[l][nt][kp][c] = pack_f16( W[row(c)][2kp], W[row(c)][2kp+1] )
//   row(c) = nt*64+c (Wih) or (c&3)*512 + nt*16 + (c>>2) (Whh)
// Also bsum = bih + bhh (fp32).
__global__ __launch_bounds__(256)
void pack_w(const float* __restrict__ Wih, const float* __restrict__ Whh,
            const float* __restrict__ bih, const float* __restrict__ bhh,
            u32* __restrict__ WpX, u32* __restrict__ WpH, float* __restrict__ bsum)
{
    __shared__ float tile[64][65];
    const int tid = threadIdx.x;
    const int blk = blockIdx.x;
    if (blk < 16) bsum[blk * 256 + tid] = bih[blk * 256 + tid] + bhh[blk * 256 + tid];

    const int mat = blk & 1;
    const int kc  = (blk >> 1) & 7;
    const int nt  = (blk >> 4) & 31;
    const int l   = blk >> 9;
    const float* W = mat ? Whh : Wih;
    u32* Wp = mat ? WpH : WpX;

    // load 64 rows x 64 k chunk into LDS (transposed: tile[c][k])
    const int c  = tid >> 2;
    const int ko = (tid & 3) * 16;
    const int grow = mat ? ((c & 3) * 512 + nt * 16 + (c >> 2))
                         : (nt * 64 + c);
    const float* src = W + ((size_t)(l * G4 + grow)) * 512 + kc * 64 + ko;
    #pragma unroll
    for (int it = 0; it < 4; ++it) {
        float4 v = ((const float4*)src)[it];
        tile[c][ko + 4*it + 0] = v.x;
        tile[c][ko + 4*it + 1] = v.y;
        tile[c][ko + 4*it + 2] = v.z;
        tile[c][ko + 4*it + 3] = v.w;
    }
    __syncthreads();
    // emit [32 kp][64 col] u32 f16-pairs
    const int kp = tid >> 3;           // 0..31
    const int cb = (tid & 7) * 8;      // col base
    u32* dst = Wp + ((size_t)((l * 32 + nt) * 256) + kc * 32 + kp) * 64 + cb;
    #pragma unroll
    for (int j = 0; j < 8; ++j)
        dst[j] = pk2(tile[cb + j][2 * kp], tile[cb + j][2 * kp + 1]);
}

__global__ __launch_bounds__(256)
void init_layer(const float* __restrict__ h0l, float* __restrict__ hbuf,
                u32* __restrict__ flags)
{
    const int idx = blockIdx.x * blockDim.x + threadIdx.x;
    if (idx < 1024) flags[idx] = 0u;
    if (idx < BB * HH) {
        const int b = idx >> 9, j = idx & 511;
        hbuf[idx] = h0l[(size_t)b * 1024 + j];
    }
}

extern "C" void kernel_launch(void* const* d_in, const int* in_sizes, int n_in,
                              void* d_out, int out_size, void* d_ws, size_t ws_size,
                              hipStream_t stream)
{
    const float* x   = (const float*)d_in[0];
    const float* h0  = (const float*)d_in[1];
    const float* c0  = (const float*)d_in[2];
    const float* Wih = (const float*)d_in[3];
    const float* bih = (const float*)d_in[4];
    const float* Whh = (const float*)d_in[5];
    const float* bhh = (const float*)d_in[6];
    float* out = (float*)d_out;
    float* ws  = (float*)d_ws;

    // ws layout, total ~10.4 MB (f16 weights)
    u32*   flags = (u32*)ws;                    // 1024 u32
    float* part  = ws + 1024;                   // 4*32*32*4 = 16384 floats
    float* hbuf  = part + 16384;                // 65536 floats
    float* gx    = hbuf + BB * HH;              // 2*128*2048 = 524288 floats
    u32*   WpX   = (u32*)(gx + 524288);         // 2 layers * 524288 u32
    u32*   WpH   = WpX + 2 * 524288;            // 2 layers * 524288 u32
    float* bsum  = (float*)(WpH + 2 * 524288);  // 4096 floats

    hipLaunchKernelGGL(pack_w, dim3(1024), dim3(256), 0, stream,
                       Wih, Whh, bih, bhh, WpX, WpH, bsum);

    for (int l = 0; l < 2; ++l) {
        hipLaunchKernelGGL(init_layer, dim3(256), dim3(256), 0, stream,
                           h0 + l * 512, hbuf, flags);
        const float* Xin  = (l == 0) ? x : (const float*)out;
        const u32*   WpXl = WpX + (size_t)l * 524288;
        const u32*   WpHl = WpH + (size_t)l * 524288;
        const float* bsl  = bsum + l * 2048;
        const float* c0l  = c0 + l * 512;
        void* args[] = {(void*)&Xin, (void*)&WpXl, (void*)&WpHl, (void*)&bsl, (void*)&c0l,
                        (void*)&hbuf, (void*)&gx, (void*)&part, (void*)&flags, (void*)&out};
        hipLaunchCooperativeKernel(reinterpret_cast<void*>(lstm_layer),
                                   dim3(NBLK), dim3(NTHR), args, 0, stream);
    }
}